// Round 3
// baseline (16821.587 us; speedup 1.0000x reference)
//
#include <hip/hip_runtime.h>
#include <math.h>

#define B_ 8
#define C_ 768
#define HW_ 1024
#define NH_ 8
#define HD_ 96
#define NPTS 2048      // PH*PW*K
#define AROUND_ 5
#define TOPK_ 5
#define MOD_ 2
#define FF_ 3072
#define TOK_ (B_*HW_)  // 8192

// ---- bilinear taps, torch grid_sample semantics (align_corners=False, zeros pad), H=W=32 ----
struct Taps { int x0,x1,y0,y1; float w00,w10,w01,w11; };
__device__ __forceinline__ Taps bilin_taps(float gx, float gy) {
  Taps t;
  float ix = ((gx+1.f)*32.f - 1.f)*0.5f;
  float iy = ((gy+1.f)*32.f - 1.f)*0.5f;
  float x0f = floorf(ix), y0f = floorf(iy);
  float wx1 = ix-x0f, wy1 = iy-y0f, wx0 = 1.f-wx1, wy0 = 1.f-wy1;
  int x0=(int)x0f, y0=(int)y0f, x1=x0+1, y1=y0+1;
  bool vx0=(x0>=0)&&(x0<=31), vx1=(x1>=0)&&(x1<=31);
  bool vy0=(y0>=0)&&(y0<=31), vy1=(y1>=0)&&(y1<=31);
  t.w00 = (vx0&&vy0) ? wx0*wy0 : 0.f;
  t.w10 = (vx1&&vy0) ? wx1*wy0 : 0.f;
  t.w01 = (vx0&&vy1) ? wx0*wy1 : 0.f;
  t.w11 = (vx1&&vy1) ? wx1*wy1 : 0.f;
  t.x0 = min(max(x0,0),31); t.x1 = min(max(x1,0),31);
  t.y0 = min(max(y0,0),31); t.y1 = min(max(y1,0),31);
  return t;
}

__device__ __forceinline__ float block_reduce_sum_256(float v, float* red) {
  int tid = threadIdx.x;
  red[tid] = v; __syncthreads();
  for (int s = 128; s > 0; s >>= 1) { if (tid < s) red[tid] += red[tid+s]; __syncthreads(); }
  float r = red[0]; __syncthreads();
  return r;
}

// ---- stage A: blockwise sample for one (modality,batch) -> pf [NPTS,C], coords [NPTS,2] ----
__global__ __launch_bounds__(256) void sample_pf_kernel(const float* __restrict__ x,
    const float* __restrict__ brand, float* __restrict__ pf, float* __restrict__ coords) {
  int n = blockIdx.x;
  int k = n & 1, pw = (n >> 1) & 31, ph = n >> 6;
  int roff = ((ph*32 + pw)*2 + k)*2;
  float r0 = brand[roff], r1 = brand[roff+1];
  const float bs = 0.0625f;
  float c0 = r0*bs + ((float)ph*bs - 1.0f);   // x coord fed to grid_sample
  float c1 = r1*bs + ((float)pw*bs - 1.0f);   // y coord
  Taps t = bilin_taps(c0, c1);
  int i00=t.y0*32+t.x0, i10=t.y0*32+t.x1, i01=t.y1*32+t.x0, i11=t.y1*32+t.x1;
  float* pfo = pf + (size_t)n*C_;
  for (int c = threadIdx.x; c < C_; c += 256) {
    const float* xc = x + (size_t)c*HW_;
    pfo[c] = t.w00*xc[i00] + t.w10*xc[i10] + t.w01*xc[i01] + t.w11*xc[i11];
  }
  if (threadIdx.x == 0) { coords[n*2] = c0; coords[n*2+1] = c1; }
}

// ---- score tail: sigmoid(h . w2 + b2) per row ----
__global__ __launch_bounds__(256) void score_reduce_kernel(const float* __restrict__ h,
    const float* __restrict__ w2, const float* __restrict__ b2, float* __restrict__ score) {
  __shared__ float red[256];
  int row = blockIdx.x, tid = threadIdx.x;
  const float* hr = h + (size_t)row*C_;
  float s = hr[tid]*w2[tid] + hr[tid+256]*w2[tid+256] + hr[tid+512]*w2[tid+512];
  s = block_reduce_sum_256(s, red);
  if (tid == 0) score[row] = 1.f/(1.f+expf(-(s + b2[0])));
}

// ---- top-5 of 2048, jax.lax.top_k semantics (stable: ties keep smaller index) ----
__global__ void topk_wave_kernel(const float* __restrict__ score, int* __restrict__ idx) {
  int lane = threadIdx.x;   // 64 lanes, one wave
  float v[32];
  #pragma unroll
  for (int i = 0; i < 32; ++i) v[i] = score[(i<<6) | lane];
  for (int t = 0; t < TOPK_; ++t) {
    float bv = v[0]; int bi = lane;
    #pragma unroll
    for (int i = 1; i < 32; ++i) { if (v[i] > bv) { bv = v[i]; bi = (i<<6)|lane; } }
    for (int off = 32; off; off >>= 1) {
      float ov = __shfl_xor(bv, off);
      int   oi = __shfl_xor(bi, off);
      if (ov > bv || (ov == bv && oi < bi)) { bv = ov; bi = oi; }
    }
    if (lane == 0) idx[t] = bi;
    if ((bi & 63) == lane) v[bi >> 6] = -1e30f;
  }
}

// ---- soft_align + modality query -> memf rows, one block per t (TOPK blocks) ----
__global__ __launch_bounds__(256) void softalign_kernel(const float* __restrict__ mainx_b,
    const float* __restrict__ pos, const float* __restrict__ pf, const float* __restrict__ coords,
    const int* __restrict__ idx, const float* __restrict__ arand_ib, const float* __restrict__ mq,
    int mod, float* __restrict__ memf_b) {
  int t = blockIdx.x;
  int tid = threadIdx.x;
  int n = idx[t];
  float px0 = coords[n*2], px1 = coords[n*2+1];
  const float* pfr = pf + (size_t)n*C_;
  float pfv[3];
  #pragma unroll
  for (int i=0;i<3;++i) pfv[i] = pfr[tid + i*256];
  __shared__ float red[256];
  float pp = block_reduce_sum_256(pfv[0]*pfv[0]+pfv[1]*pfv[1]+pfv[2]*pfv[2], red);
  float embr[AROUND_][3];
  float num_a[AROUND_], aa_a[AROUND_];
  for (int a=0; a<AROUND_; ++a) {
    int ar = (a*TOPK_ + t)*2;
    float g0 = px0 + (arand_ib[ar]*2.f - 0.5f)*0.2f;
    float g1 = px1 + (arand_ib[ar+1]*2.f - 0.5f)*0.2f;
    g0 = fminf(fmaxf(g0,-1.f),1.f);
    g1 = fminf(fmaxf(g1,-1.f),1.f);
    Taps tp = bilin_taps(g0, g1);
    int i00=tp.y0*32+tp.x0, i10=tp.y0*32+tp.x1, i01=tp.y1*32+tp.x0, i11=tp.y1*32+tp.x1;
    float s_num = 0.f, s_aa = 0.f;
    #pragma unroll
    for (int i=0;i<3;++i) {
      int c = tid + i*256;
      const float* mc = mainx_b + (size_t)c*HW_;
      float af = tp.w00*mc[i00] + tp.w10*mc[i10] + tp.w01*mc[i01] + tp.w11*mc[i11];
      float em = tp.w00*pos[(size_t)i00*C_+c] + tp.w10*pos[(size_t)i10*C_+c]
               + tp.w01*pos[(size_t)i01*C_+c] + tp.w11*pos[(size_t)i11*C_+c];
      embr[a][i] = em;
      s_num += pfv[i]*af;
      s_aa  += af*af;
    }
    num_a[a] = block_reduce_sum_256(s_num, red);
    aa_a[a]  = block_reduce_sum_256(s_aa, red);
  }
  float pn = fmaxf(sqrtf(pp), 1e-8f);
  float w[AROUND_]; float mx = -1e30f;
  #pragma unroll
  for (int a=0;a<AROUND_;++a){ float den = pn * fmaxf(sqrtf(aa_a[a]),1e-8f); w[a]=num_a[a]/den; mx=fmaxf(mx,w[a]); }
  float se = 0.f;
  #pragma unroll
  for (int a=0;a<AROUND_;++a){ w[a]=expf(w[a]-mx); se+=w[a]; }
  float inv = 1.f/se;
  float* mo = memf_b + (size_t)(mod*TOPK_ + t)*C_;
  #pragma unroll
  for (int i=0;i<3;++i) {
    int c = tid + i*256;
    float o = pfv[i];
    #pragma unroll
    for (int a=0;a<AROUND_;++a) o += embr[a][i]*(w[a]*inv);
    o += mq[(size_t)(mod+1)*C_ + c];
    mo[c] = o;
  }
}

// ---- generic fp32 GEMM: C[M,N] = act(A[M,K] @ B[K,N] + bias), 64x64x16 tile ----
#define BM 64
#define BN 64
#define BK 16
__global__ __launch_bounds__(256) void gemm_kernel(const float* __restrict__ A, int lda,
    const float* __restrict__ Bw, int ldb, const float* __restrict__ bias,
    float* __restrict__ Cm, int ldc, int M, int N, int K, int act) {
  __shared__ float As[BK][BM];
  __shared__ float Bs[BK][BN];
  int tid = threadIdx.x;
  int bm = blockIdx.y * BM, bn = blockIdx.x * BN;
  int arw = tid >> 2, acl = (tid & 3) << 2;
  int brw = tid >> 4, bcl = (tid & 15) << 2;
  int ty = tid >> 4, tx = tid & 15;
  float acc[4][4] = {{0.f}};
  for (int k0 = 0; k0 < K; k0 += BK) {
    float a0=0.f,a1=0.f,a2=0.f,a3=0.f;
    if (bm + arw < M) {
      const float* ap = A + (size_t)(bm+arw)*lda + k0 + acl;
      a0=ap[0]; a1=ap[1]; a2=ap[2]; a3=ap[3];
    }
    As[acl+0][arw]=a0; As[acl+1][arw]=a1; As[acl+2][arw]=a2; As[acl+3][arw]=a3;
    const float* bp = Bw + (size_t)(k0+brw)*ldb + bn + bcl;
    Bs[brw][bcl+0]=bp[0]; Bs[brw][bcl+1]=bp[1]; Bs[brw][bcl+2]=bp[2]; Bs[brw][bcl+3]=bp[3];
    __syncthreads();
    #pragma unroll
    for (int kk = 0; kk < BK; ++kk) {
      float4 av = *reinterpret_cast<const float4*>(&As[kk][ty<<2]);
      float4 bv = *reinterpret_cast<const float4*>(&Bs[kk][tx<<2]);
      acc[0][0]+=av.x*bv.x; acc[0][1]+=av.x*bv.y; acc[0][2]+=av.x*bv.z; acc[0][3]+=av.x*bv.w;
      acc[1][0]+=av.y*bv.x; acc[1][1]+=av.y*bv.y; acc[1][2]+=av.y*bv.z; acc[1][3]+=av.y*bv.w;
      acc[2][0]+=av.z*bv.x; acc[2][1]+=av.z*bv.y; acc[2][2]+=av.z*bv.z; acc[2][3]+=av.z*bv.w;
      acc[3][0]+=av.w*bv.x; acc[3][1]+=av.w*bv.y; acc[3][2]+=av.w*bv.z; acc[3][3]+=av.w*bv.w;
    }
    __syncthreads();
  }
  #pragma unroll
  for (int i=0;i<4;++i) {
    int r = bm + (ty<<2) + i;
    if (r >= M) continue;
    float* cp = Cm + (size_t)r*ldc + bn + (tx<<2);
    #pragma unroll
    for (int j=0;j<4;++j) {
      float v = acc[i][j] + bias[bn + (tx<<2) + j];
      if (act) v = fmaxf(v, 0.f);
      cp[j] = v;
    }
  }
}

// ---- self-attention for one batch: qkv [1024,2304]; one block per (h,q); o [1024,768] ----
__global__ __launch_bounds__(128) void self_attn_kernel(const float* __restrict__ qkv,
    float* __restrict__ o) {
  int gid = blockIdx.x;            // h*1024 + q
  int q = gid & (HW_-1);
  int h = gid >> 10;
  int tid = threadIdx.x;
  __shared__ float qs[HD_];
  __shared__ float sc[HW_];
  __shared__ float red[128];
  const float* qp = qkv + (size_t)q*2304 + h*HD_;
  if (tid < HD_) qs[tid] = qp[tid];
  __syncthreads();
  const float scale = 0.10206207261596577f;  // 1/sqrt(96)
  for (int j = tid; j < HW_; j += 128) {
    const float* kp = qkv + (size_t)j*2304 + C_ + h*HD_;
    float s = 0.f;
    #pragma unroll 8
    for (int d = 0; d < HD_; ++d) s += qs[d]*kp[d];
    sc[j] = s*scale;
  }
  __syncthreads();
  float m = -1e30f;
  for (int j = tid; j < HW_; j += 128) m = fmaxf(m, sc[j]);
  red[tid]=m; __syncthreads();
  for (int s=64;s>0;s>>=1){ if(tid<s) red[tid]=fmaxf(red[tid],red[tid+s]); __syncthreads(); }
  m = red[0]; __syncthreads();
  float sum = 0.f;
  for (int j = tid; j < HW_; j += 128){ float e = expf(sc[j]-m); sc[j]=e; sum+=e; }
  red[tid]=sum; __syncthreads();
  for (int s=64;s>0;s>>=1){ if(tid<s) red[tid]+=red[tid+s]; __syncthreads(); }
  float inv = 1.f/red[0];
  if (tid < HD_) {
    const float* vp = qkv + 2*C_ + h*HD_ + tid;
    float acc = 0.f;
    for (int j = 0; j < HW_; ++j) acc += sc[j]*vp[(size_t)j*2304];
    o[(size_t)q*C_ + h*HD_ + tid] = acc*inv;
  }
}

// ---- cross-attention over 10 memory tokens for one batch, IN PLACE on qb rows ----
__global__ __launch_bounds__(128) void cross_attn_kernel(float* __restrict__ qb,
    const float* __restrict__ kvm, int b) {
  int gid = blockIdx.x;                  // row within batch
  int tid = threadIdx.x;
  __shared__ float sc[16];
  __shared__ float qs[C_];
  float* qp = qb + (size_t)gid*C_;
  for (int c = tid; c < C_; c += 128) qs[c] = qp[c];
  __syncthreads();
  const float scale = 0.10206207261596577f;
  for (int h = 0; h < NH_; ++h) {
    if (tid < 10) {
      const float* kp = kvm + (size_t)(b*10 + tid)*1536 + h*HD_;
      float s = 0.f;
      for (int d = 0; d < HD_; ++d) s += qs[h*HD_+d]*kp[d];
      sc[tid] = s*scale;
    }
    __syncthreads();
    if (tid == 0) {
      float m = -1e30f;
      for (int j=0;j<10;++j) m = fmaxf(m, sc[j]);
      float se = 0.f;
      for (int j=0;j<10;++j){ sc[j]=expf(sc[j]-m); se+=sc[j]; }
      float inv = 1.f/se;
      for (int j=0;j<10;++j) sc[j]*=inv;
    }
    __syncthreads();
    if (tid < HD_) {
      const float* vp = kvm + (size_t)(b*10)*1536 + C_ + h*HD_ + tid;
      float acc = 0.f;
      for (int j=0;j<10;++j) acc += sc[j]*vp[(size_t)j*1536];
      qp[h*HD_+tid] = acc;
    }
    __syncthreads();
  }
}

// ---- tgt init: mainx(BCHW->B,HW,C) + modality_query[0] + pos ----
__global__ void tgt0_kernel(const float* __restrict__ mainx, const float* __restrict__ mq,
                            const float* __restrict__ pos, float* __restrict__ tgt) {
  size_t i = (size_t)blockIdx.x*256 + threadIdx.x;
  if (i >= (size_t)TOK_*C_) return;
  int c = (int)(i % C_);
  size_t bt = i / C_;
  int tpos = (int)(bt % HW_);
  int b = (int)(bt / HW_);
  tgt[i] = mainx[((size_t)b*C_ + c)*HW_ + tpos] + mq[c] + pos[(size_t)tpos*C_ + c];
}

// ---- residual + layernorm (in place on tgt rows) ----
__global__ __launch_bounds__(256) void ln_res_kernel(float* __restrict__ tgt, const float* __restrict__ add,
    const float* __restrict__ w, const float* __restrict__ bvec) {
  __shared__ float red[256];
  int row = blockIdx.x, tid = threadIdx.x;
  float* tp = tgt + (size_t)row*C_;
  const float* ap = add + (size_t)row*C_;
  float x[3]; float s = 0.f, s2 = 0.f;
  #pragma unroll
  for (int i=0;i<3;++i){ int c=tid+i*256; float v=tp[c]+ap[c]; x[i]=v; s+=v; s2+=v*v; }
  s  = block_reduce_sum_256(s,  red);
  s2 = block_reduce_sum_256(s2, red);
  float mean = s * (1.f/C_);
  float var  = s2 * (1.f/C_) - mean*mean;
  float rstd = rsqrtf(var + 1e-5f);
  #pragma unroll
  for (int i=0;i<3;++i){ int c=tid+i*256; tp[c] = (x[i]-mean)*rstd*w[c] + bvec[c]; }
}

// ---- final transpose B,HW,C -> B,C,H,W ----
__global__ void out_kernel(const float* __restrict__ tgt, float* __restrict__ out) {
  size_t i = (size_t)blockIdx.x*256 + threadIdx.x;
  if (i >= (size_t)B_*C_*HW_) return;
  int wcol = (int)(i & 31);
  int hrow = (int)((i >> 5) & 31);
  size_t rest = i >> 10;
  int c = (int)(rest % C_);
  int b = (int)(rest / C_);
  out[i] = tgt[((size_t)b*HW_ + hrow*32 + wcol)*C_ + c];
}

extern "C" void kernel_launch(void* const* d_in, const int* in_sizes, int n_in,
                              void* d_out, int out_size, void* d_ws, size_t ws_size,
                              hipStream_t stream) {
  const float* mainx   = (const float*)d_in[0];
  const float* other[2]= {(const float*)d_in[1], (const float*)d_in[2]};
  const float* pos     = (const float*)d_in[3];
  const float* mq      = (const float*)d_in[4];
  const float* s_w1    = (const float*)d_in[5];
  const float* s_b1    = (const float*)d_in[6];
  const float* s_w2    = (const float*)d_in[7];
  const float* s_b2    = (const float*)d_in[8];
  const float* sa_in_w = (const float*)d_in[9];
  const float* sa_in_b = (const float*)d_in[10];
  const float* sa_out_w= (const float*)d_in[11];
  const float* sa_out_b= (const float*)d_in[12];
  const float* ca_in_w = (const float*)d_in[13];
  const float* ca_in_b = (const float*)d_in[14];
  const float* ca_out_w= (const float*)d_in[15];
  const float* ca_out_b= (const float*)d_in[16];
  const float* ff1_w   = (const float*)d_in[17];
  const float* ff1_b   = (const float*)d_in[18];
  const float* ff2_w   = (const float*)d_in[19];
  const float* ff2_b   = (const float*)d_in[20];
  const float* ln_w    = (const float*)d_in[21];
  const float* ln_b    = (const float*)d_in[22];
  const float* brand   = (const float*)d_in[23];
  const float* arand   = (const float*)d_in[24];

  // ---- workspace layout (fp32), ~59.5 MB peak ----
  float* tgt    = (float*)d_ws;                   // 6,291,456
  float* Areg   = tgt + 6291456;                  // 8,388,608 shared region
  float* kvm    = Areg + 8388608;                 // 122,880  [80,1536]
  float* memf   = kvm + 122880;                   // 61,440   [80,768]
  float* coords = memf + 61440;                   // 4,096    [2048,2]
  float* score  = coords + 4096;                  // 2,048
  int*   idxb   = (int*)(score + 2048);           // 64

  // sub-pointers into Areg
  float* pf    = Areg;                // [2048,768]
  float* hbuf  = Areg + 1572864;      // [2048,768]
  float* qkvb  = Areg;                // [1024,2304]
  float* oattb = Areg + 2359296;      // [1024,768]
  float* tmpb  = Areg + 3145728;      // [1024,768]
  float* qbb   = Areg;                // [1024,768]
  float* tmpb2 = Areg + 786432;       // [1024,768]
  float* ffh   = Areg;                // [2048,3072]
  float* tmpc  = Areg + 6291456;      // [2048,768]

  // ---- stage A: per (modality, batch) ----
  for (int i = 0; i < 2; ++i) {
    for (int b = 0; b < B_; ++b) {
      sample_pf_kernel<<<NPTS, 256, 0, stream>>>(
          other[i] + (size_t)b*C_*HW_, brand + (size_t)(i*B_ + b)*4096, pf, coords);
      gemm_kernel<<<dim3(C_/BN, NPTS/BM), 256, 0, stream>>>(pf, C_, s_w1, C_, s_b1,
          hbuf, C_, NPTS, C_, C_, 1);
      score_reduce_kernel<<<NPTS, 256, 0, stream>>>(hbuf, s_w2, s_b2, score);
      topk_wave_kernel<<<1, 64, 0, stream>>>(score, idxb);
      softalign_kernel<<<TOPK_, 256, 0, stream>>>(mainx + (size_t)b*C_*HW_, pos, pf, coords,
          idxb, arand + (size_t)(i*B_ + b)*AROUND_*TOPK_*2, mq, i, memf + (size_t)b*MOD_*TOPK_*C_);
    }
  }

  // ---- stage B ----
  size_t total = (size_t)TOK_*C_;
  tgt0_kernel<<<(int)((total+255)/256), 256, 0, stream>>>(mainx, mq, pos, tgt);

  for (int l = 0; l < 2; ++l) {
    // self-attention, per batch
    for (int b = 0; b < B_; ++b) {
      float* tgtb = tgt + (size_t)b*HW_*C_;
      gemm_kernel<<<dim3(3*C_/BN, HW_/BM), 256, 0, stream>>>(tgtb, C_,
          sa_in_w + (size_t)l*C_*3*C_, 3*C_, sa_in_b + (size_t)l*3*C_, qkvb, 3*C_, HW_, 3*C_, C_, 0);
      self_attn_kernel<<<NH_*HW_, 128, 0, stream>>>(qkvb, oattb);
      gemm_kernel<<<dim3(C_/BN, HW_/BM), 256, 0, stream>>>(oattb, C_,
          sa_out_w + (size_t)l*C_*C_, C_, sa_out_b + (size_t)l*C_, tmpb, C_, HW_, C_, C_, 0);
      ln_res_kernel<<<HW_, 256, 0, stream>>>(tgtb, tmpb,
          ln_w + (size_t)(l*3+0)*C_, ln_b + (size_t)(l*3+0)*C_);
    }

    // cross-attention: KV once, then per batch
    gemm_kernel<<<dim3(2*C_/BN, 2), 256, 0, stream>>>(memf, C_,
        ca_in_w + (size_t)l*C_*3*C_ + C_, 3*C_, ca_in_b + (size_t)l*3*C_ + C_, kvm, 2*C_,
        B_*MOD_*TOPK_, 2*C_, C_, 0);
    for (int b = 0; b < B_; ++b) {
      float* tgtb = tgt + (size_t)b*HW_*C_;
      gemm_kernel<<<dim3(C_/BN, HW_/BM), 256, 0, stream>>>(tgtb, C_,
          ca_in_w + (size_t)l*C_*3*C_, 3*C_, ca_in_b + (size_t)l*3*C_, qbb, C_, HW_, C_, C_, 0);
      cross_attn_kernel<<<HW_, 128, 0, stream>>>(qbb, kvm, b);
      gemm_kernel<<<dim3(C_/BN, HW_/BM), 256, 0, stream>>>(qbb, C_,
          ca_out_w + (size_t)l*C_*C_, C_, ca_out_b + (size_t)l*C_, tmpb2, C_, HW_, C_, C_, 0);
      ln_res_kernel<<<HW_, 256, 0, stream>>>(tgtb, tmpb2,
          ln_w + (size_t)(l*3+1)*C_, ln_b + (size_t)(l*3+1)*C_);
    }

    // FFN in 4 chunks of 2048 rows, LN per chunk (row-local)
    for (int ch = 0; ch < 4; ++ch) {
      float* tgtc = tgt + (size_t)ch*2048*C_;
      gemm_kernel<<<dim3(FF_/BN, 2048/BM), 256, 0, stream>>>(tgtc, C_,
          ff1_w + (size_t)l*C_*FF_, FF_, ff1_b + (size_t)l*FF_, ffh, FF_, 2048, FF_, C_, 1);
      gemm_kernel<<<dim3(C_/BN, 2048/BM), 256, 0, stream>>>(ffh, FF_,
          ff2_w + (size_t)l*FF_*C_, C_, ff2_b + (size_t)l*C_, tmpc, C_, 2048, C_, FF_, 0);
      ln_res_kernel<<<2048, 256, 0, stream>>>(tgtc, tmpc,
          ln_w + (size_t)(l*3+2)*C_, ln_b + (size_t)(l*3+2)*C_);
    }
  }

  out_kernel<<<(int)((total+255)/256), 256, 0, stream>>>(tgt, (float*)d_out);
}

// Round 4
// 10209.278 us; speedup vs baseline: 1.6477x; 1.6477x over previous
//
#include <hip/hip_runtime.h>
#include <hip/hip_bf16.h>
#include <math.h>

typedef __hip_bfloat16 hbf16;

#define B_ 8
#define C_ 768
#define HW_ 1024
#define NH_ 8
#define HD_ 96
#define NPTS 2048      // PH*PW*K
#define AROUND_ 5
#define TOPK_ 5
#define MOD_ 2
#define FF_ 3072
#define TOK_ (B_*HW_)  // 8192

typedef __attribute__((ext_vector_type(8))) short short8v;
typedef __attribute__((ext_vector_type(4))) float f32x4;

__device__ __forceinline__ float b2f(hbf16 v){ return __bfloat162float(v); }

// ---- bilinear taps, torch grid_sample semantics (align_corners=False, zeros pad), H=W=32 ----
struct Taps { int x0,x1,y0,y1; float w00,w10,w01,w11; };
__device__ __forceinline__ Taps bilin_taps(float gx, float gy) {
  Taps t;
  float ix = ((gx+1.f)*32.f - 1.f)*0.5f;
  float iy = ((gy+1.f)*32.f - 1.f)*0.5f;
  float x0f = floorf(ix), y0f = floorf(iy);
  float wx1 = ix-x0f, wy1 = iy-y0f, wx0 = 1.f-wx1, wy0 = 1.f-wy1;
  int x0=(int)x0f, y0=(int)y0f, x1=x0+1, y1=y0+1;
  bool vx0=(x0>=0)&&(x0<=31), vx1=(x1>=0)&&(x1<=31);
  bool vy0=(y0>=0)&&(y0<=31), vy1=(y1>=0)&&(y1<=31);
  t.w00 = (vx0&&vy0) ? wx0*wy0 : 0.f;
  t.w10 = (vx1&&vy0) ? wx1*wy0 : 0.f;
  t.w01 = (vx0&&vy1) ? wx0*wy1 : 0.f;
  t.w11 = (vx1&&vy1) ? wx1*wy1 : 0.f;
  t.x0 = min(max(x0,0),31); t.x1 = min(max(x1,0),31);
  t.y0 = min(max(y0,0),31); t.y1 = min(max(y1,0),31);
  return t;
}

__device__ __forceinline__ float block_reduce_sum_256(float v, float* red) {
  int tid = threadIdx.x;
  red[tid] = v; __syncthreads();
  for (int s = 128; s > 0; s >>= 1) { if (tid < s) red[tid] += red[tid+s]; __syncthreads(); }
  float r = red[0]; __syncthreads();
  return r;
}

// ---- fp32 -> bf16 elementwise convert (n multiple of 4) ----
__global__ __launch_bounds__(256) void f2b_kernel(const float* __restrict__ in,
    hbf16* __restrict__ out, int n) {
  int i = (blockIdx.x*256 + threadIdx.x)*4;
  if (i >= n) return;
  float4 v = *(const float4*)&in[i];
  out[i+0] = __float2bfloat16(v.x);
  out[i+1] = __float2bfloat16(v.y);
  out[i+2] = __float2bfloat16(v.z);
  out[i+3] = __float2bfloat16(v.w);
}

// ---- stage A: blockwise sample for one (modality,batch) -> pf [NPTS,C], coords [NPTS,2] ----
__global__ __launch_bounds__(256) void sample_pf_kernel(const float* __restrict__ x,
    const float* __restrict__ brand, float* __restrict__ pf, float* __restrict__ coords) {
  int n = blockIdx.x;
  int k = n & 1, pw = (n >> 1) & 31, ph = n >> 6;
  int roff = ((ph*32 + pw)*2 + k)*2;
  float r0 = brand[roff], r1 = brand[roff+1];
  const float bs = 0.0625f;
  float c0 = r0*bs + ((float)ph*bs - 1.0f);
  float c1 = r1*bs + ((float)pw*bs - 1.0f);
  Taps t = bilin_taps(c0, c1);
  int i00=t.y0*32+t.x0, i10=t.y0*32+t.x1, i01=t.y1*32+t.x0, i11=t.y1*32+t.x1;
  float* pfo = pf + (size_t)n*C_;
  for (int c = threadIdx.x; c < C_; c += 256) {
    const float* xc = x + (size_t)c*HW_;
    pfo[c] = t.w00*xc[i00] + t.w10*xc[i10] + t.w01*xc[i01] + t.w11*xc[i11];
  }
  if (threadIdx.x == 0) { coords[n*2] = c0; coords[n*2+1] = c1; }
}

// ---- score tail: sigmoid(h . w2 + b2) per row ----
__global__ __launch_bounds__(256) void score_reduce_kernel(const float* __restrict__ h,
    const float* __restrict__ w2, const float* __restrict__ b2, float* __restrict__ score) {
  __shared__ float red[256];
  int row = blockIdx.x, tid = threadIdx.x;
  const float* hr = h + (size_t)row*C_;
  float s = hr[tid]*w2[tid] + hr[tid+256]*w2[tid+256] + hr[tid+512]*w2[tid+512];
  s = block_reduce_sum_256(s, red);
  if (tid == 0) score[row] = 1.f/(1.f+expf(-(s + b2[0])));
}

// ---- top-5 of 2048, jax.lax.top_k semantics (stable: ties keep smaller index) ----
__global__ void topk_wave_kernel(const float* __restrict__ score, int* __restrict__ idx) {
  int lane = threadIdx.x;   // 64 lanes, one wave
  float v[32];
  #pragma unroll
  for (int i = 0; i < 32; ++i) v[i] = score[(i<<6) | lane];
  for (int t = 0; t < TOPK_; ++t) {
    float bv = v[0]; int bi = lane;
    #pragma unroll
    for (int i = 1; i < 32; ++i) { if (v[i] > bv) { bv = v[i]; bi = (i<<6)|lane; } }
    for (int off = 32; off; off >>= 1) {
      float ov = __shfl_xor(bv, off);
      int   oi = __shfl_xor(bi, off);
      if (ov > bv || (ov == bv && oi < bi)) { bv = ov; bi = oi; }
    }
    if (lane == 0) idx[t] = bi;
    if ((bi & 63) == lane) v[bi >> 6] = -1e30f;
  }
}

// ---- soft_align + modality query -> memf rows, one block per t ----
__global__ __launch_bounds__(256) void softalign_kernel(const float* __restrict__ mainx_b,
    const float* __restrict__ pos, const float* __restrict__ pf, const float* __restrict__ coords,
    const int* __restrict__ idx, const float* __restrict__ arand_ib, const float* __restrict__ mq,
    int mod, float* __restrict__ memf_b) {
  int t = blockIdx.x;
  int tid = threadIdx.x;
  int n = idx[t];
  float px0 = coords[n*2], px1 = coords[n*2+1];
  const float* pfr = pf + (size_t)n*C_;
  float pfv[3];
  #pragma unroll
  for (int i=0;i<3;++i) pfv[i] = pfr[tid + i*256];
  __shared__ float red[256];
  float pp = block_reduce_sum_256(pfv[0]*pfv[0]+pfv[1]*pfv[1]+pfv[2]*pfv[2], red);
  float embr[AROUND_][3];
  float num_a[AROUND_], aa_a[AROUND_];
  for (int a=0; a<AROUND_; ++a) {
    int ar = (a*TOPK_ + t)*2;
    float g0 = px0 + (arand_ib[ar]*2.f - 0.5f)*0.2f;
    float g1 = px1 + (arand_ib[ar+1]*2.f - 0.5f)*0.2f;
    g0 = fminf(fmaxf(g0,-1.f),1.f);
    g1 = fminf(fmaxf(g1,-1.f),1.f);
    Taps tp = bilin_taps(g0, g1);
    int i00=tp.y0*32+tp.x0, i10=tp.y0*32+tp.x1, i01=tp.y1*32+tp.x0, i11=tp.y1*32+tp.x1;
    float s_num = 0.f, s_aa = 0.f;
    #pragma unroll
    for (int i=0;i<3;++i) {
      int c = tid + i*256;
      const float* mc = mainx_b + (size_t)c*HW_;
      float af = tp.w00*mc[i00] + tp.w10*mc[i10] + tp.w01*mc[i01] + tp.w11*mc[i11];
      float em = tp.w00*pos[(size_t)i00*C_+c] + tp.w10*pos[(size_t)i10*C_+c]
               + tp.w01*pos[(size_t)i01*C_+c] + tp.w11*pos[(size_t)i11*C_+c];
      embr[a][i] = em;
      s_num += pfv[i]*af;
      s_aa  += af*af;
    }
    num_a[a] = block_reduce_sum_256(s_num, red);
    aa_a[a]  = block_reduce_sum_256(s_aa, red);
  }
  float pn = fmaxf(sqrtf(pp), 1e-8f);
  float w[AROUND_]; float mx = -1e30f;
  #pragma unroll
  for (int a=0;a<AROUND_;++a){ float den = pn * fmaxf(sqrtf(aa_a[a]),1e-8f); w[a]=num_a[a]/den; mx=fmaxf(mx,w[a]); }
  float se = 0.f;
  #pragma unroll
  for (int a=0;a<AROUND_;++a){ w[a]=expf(w[a]-mx); se+=w[a]; }
  float inv = 1.f/se;
  float* mo = memf_b + (size_t)(mod*TOPK_ + t)*C_;
  #pragma unroll
  for (int i=0;i<3;++i) {
    int c = tid + i*256;
    float o = pfv[i];
    #pragma unroll
    for (int a=0;a<AROUND_;++a) o += embr[a][i]*(w[a]*inv);
    o += mq[(size_t)(mod+1)*C_ + c];
    mo[c] = o;
  }
}

// ---- generic fp32 GEMM (kept for score MLP + tiny kv GEMM) ----
#define BM 64
#define BN 64
#define BK 16
__global__ __launch_bounds__(256) void gemm_kernel(const float* __restrict__ A, int lda,
    const float* __restrict__ Bw, int ldb, const float* __restrict__ bias,
    float* __restrict__ Cm, int ldc, int M, int N, int K, int act) {
  __shared__ float As[BK][BM];
  __shared__ float Bs[BK][BN];
  int tid = threadIdx.x;
  int bm = blockIdx.y * BM, bn = blockIdx.x * BN;
  int arw = tid >> 2, acl = (tid & 3) << 2;
  int brw = tid >> 4, bcl = (tid & 15) << 2;
  int ty = tid >> 4, tx = tid & 15;
  float acc[4][4] = {{0.f}};
  for (int k0 = 0; k0 < K; k0 += BK) {
    float a0=0.f,a1=0.f,a2=0.f,a3=0.f;
    if (bm + arw < M) {
      const float* ap = A + (size_t)(bm+arw)*lda + k0 + acl;
      a0=ap[0]; a1=ap[1]; a2=ap[2]; a3=ap[3];
    }
    As[acl+0][arw]=a0; As[acl+1][arw]=a1; As[acl+2][arw]=a2; As[acl+3][arw]=a3;
    const float* bp = Bw + (size_t)(k0+brw)*ldb + bn + bcl;
    Bs[brw][bcl+0]=bp[0]; Bs[brw][bcl+1]=bp[1]; Bs[brw][bcl+2]=bp[2]; Bs[brw][bcl+3]=bp[3];
    __syncthreads();
    #pragma unroll
    for (int kk = 0; kk < BK; ++kk) {
      float4 av = *reinterpret_cast<const float4*>(&As[kk][ty<<2]);
      float4 bv = *reinterpret_cast<const float4*>(&Bs[kk][tx<<2]);
      acc[0][0]+=av.x*bv.x; acc[0][1]+=av.x*bv.y; acc[0][2]+=av.x*bv.z; acc[0][3]+=av.x*bv.w;
      acc[1][0]+=av.y*bv.x; acc[1][1]+=av.y*bv.y; acc[1][2]+=av.y*bv.z; acc[1][3]+=av.y*bv.w;
      acc[2][0]+=av.z*bv.x; acc[2][1]+=av.z*bv.y; acc[2][2]+=av.z*bv.z; acc[2][3]+=av.z*bv.w;
      acc[3][0]+=av.w*bv.x; acc[3][1]+=av.w*bv.y; acc[3][2]+=av.w*bv.z; acc[3][3]+=av.w*bv.w;
    }
    __syncthreads();
  }
  #pragma unroll
  for (int i=0;i<4;++i) {
    int r = bm + (ty<<2) + i;
    if (r >= M) continue;
    float* cp = Cm + (size_t)r*ldc + bn + (tx<<2);
    #pragma unroll
    for (int j=0;j<4;++j) {
      float v = acc[i][j] + bias[bn + (tx<<2) + j];
      if (act) v = fmaxf(v, 0.f);
      cp[j] = v;
    }
  }
}

// ---- bf16 MFMA GEMM: C[M,N] = act(A[M,K]bf16 @ B[K,N]bf16 + bias), 128x128 tile, BK=32 ----
// grid = (N/128, M/128), 256 threads (4 waves, each computes a 64x64 quadrant via 4x4 MFMA tiles)
__global__ __launch_bounds__(256) void gemm_mfma(const short* __restrict__ A, int lda,
    const short* __restrict__ Bw, int ldb, const float* __restrict__ bias,
    hbf16* __restrict__ Cm, int ldc, int K, int act) {
  __shared__ short As[128*40];   // row m, k-contiguous, stride 40 (80B, 16B aligned)
  __shared__ short Bs[128*40];   // row n, k-contiguous
  int tid = threadIdx.x;
  int lane = tid & 63, w = tid >> 6;
  int wr = (w >> 1) * 64, wc = (w & 1) * 64;
  int m16 = lane & 15, q8 = (lane >> 4) * 8;
  int bm = blockIdx.y * 128, bn = blockIdx.x * 128;
  int ar = tid >> 2, ac = (tid & 3) * 8;        // A staging: 64 rows/pass, 8 k each
  int bnn = tid & 127, bkh = (tid >> 7) * 16;   // B staging: 128 cols, 16 k each
  f32x4 acc[4][4] = {};
  for (int k0 = 0; k0 < K; k0 += 32) {
    *(short8v*)&As[ar*40 + ac]      = *(const short8v*)&A[(size_t)(bm+ar)*lda + k0 + ac];
    *(short8v*)&As[(ar+64)*40 + ac] = *(const short8v*)&A[(size_t)(bm+ar+64)*lda + k0 + ac];
    short bv[16];
    #pragma unroll
    for (int j = 0; j < 16; ++j) bv[j] = Bw[(size_t)(k0+bkh+j)*ldb + bn + bnn];
    *(short8v*)&Bs[bnn*40 + bkh]     = *(short8v*)&bv[0];
    *(short8v*)&Bs[bnn*40 + bkh + 8] = *(short8v*)&bv[8];
    __syncthreads();
    short8v af[4], bf[4];
    #pragma unroll
    for (int i=0;i<4;++i) af[i] = *(const short8v*)&As[(wr + i*16 + m16)*40 + q8];
    #pragma unroll
    for (int j=0;j<4;++j) bf[j] = *(const short8v*)&Bs[(wc + j*16 + m16)*40 + q8];
    #pragma unroll
    for (int i=0;i<4;++i)
      #pragma unroll
      for (int j=0;j<4;++j)
        acc[i][j] = __builtin_amdgcn_mfma_f32_16x16x32_bf16(af[i], bf[j], acc[i][j], 0, 0, 0);
    __syncthreads();
  }
  #pragma unroll
  for (int j=0;j<4;++j) {
    int col = bn + wc + j*16 + m16;
    float bs = bias[col];
    #pragma unroll
    for (int i=0;i<4;++i) {
      int row0 = bm + wr + i*16 + (lane>>4)*4;
      #pragma unroll
      for (int r=0;r<4;++r) {
        float v = acc[i][j][r] + bs;
        if (act) v = fmaxf(v, 0.f);
        Cm[(size_t)(row0+r)*ldc + col] = __float2bfloat16(v);
      }
    }
  }
}

// ---- self-attention for one batch: qkv [1024,2304] bf16; one block per (h,q); o bf16 ----
__global__ __launch_bounds__(128) void self_attn_kernel(const hbf16* __restrict__ qkv,
    hbf16* __restrict__ o) {
  int gid = blockIdx.x;            // h*1024 + q
  int q = gid & (HW_-1);
  int h = gid >> 10;
  int tid = threadIdx.x;
  __shared__ float qs[HD_];
  __shared__ float sc[HW_];
  __shared__ float red[128];
  const hbf16* qp = qkv + (size_t)q*2304 + h*HD_;
  if (tid < HD_) qs[tid] = b2f(qp[tid]);
  __syncthreads();
  const float scale = 0.10206207261596577f;  // 1/sqrt(96)
  for (int j = tid; j < HW_; j += 128) {
    const hbf16* kp = qkv + (size_t)j*2304 + C_ + h*HD_;
    float s = 0.f;
    #pragma unroll 8
    for (int d = 0; d < HD_; ++d) s += qs[d]*b2f(kp[d]);
    sc[j] = s*scale;
  }
  __syncthreads();
  float m = -1e30f;
  for (int j = tid; j < HW_; j += 128) m = fmaxf(m, sc[j]);
  red[tid]=m; __syncthreads();
  for (int s=64;s>0;s>>=1){ if(tid<s) red[tid]=fmaxf(red[tid],red[tid+s]); __syncthreads(); }
  m = red[0]; __syncthreads();
  float sum = 0.f;
  for (int j = tid; j < HW_; j += 128){ float e = expf(sc[j]-m); sc[j]=e; sum+=e; }
  red[tid]=sum; __syncthreads();
  for (int s=64;s>0;s>>=1){ if(tid<s) red[tid]+=red[tid+s]; __syncthreads(); }
  float inv = 1.f/red[0];
  if (tid < HD_) {
    const hbf16* vp = qkv + 2*C_ + h*HD_ + tid;
    float acc = 0.f;
    for (int j = 0; j < HW_; ++j) acc += sc[j]*b2f(vp[(size_t)j*2304]);
    o[(size_t)q*C_ + h*HD_ + tid] = __float2bfloat16(acc*inv);
  }
}

// ---- cross-attention over 10 memory tokens for one batch, IN PLACE on bf16 q rows ----
__global__ __launch_bounds__(128) void cross_attn_kernel(hbf16* __restrict__ qb,
    const float* __restrict__ kvm, int b) {
  int gid = blockIdx.x;                  // row within batch
  int tid = threadIdx.x;
  __shared__ float sc[16];
  __shared__ float qs[C_];
  hbf16* qp = qb + (size_t)gid*C_;
  for (int c = tid; c < C_; c += 128) qs[c] = b2f(qp[c]);
  __syncthreads();
  const float scale = 0.10206207261596577f;
  for (int h = 0; h < NH_; ++h) {
    if (tid < 10) {
      const float* kp = kvm + (size_t)(b*10 + tid)*1536 + h*HD_;
      float s = 0.f;
      for (int d = 0; d < HD_; ++d) s += qs[h*HD_+d]*kp[d];
      sc[tid] = s*scale;
    }
    __syncthreads();
    if (tid == 0) {
      float m = -1e30f;
      for (int j=0;j<10;++j) m = fmaxf(m, sc[j]);
      float se = 0.f;
      for (int j=0;j<10;++j){ sc[j]=expf(sc[j]-m); se+=sc[j]; }
      float inv = 1.f/se;
      for (int j=0;j<10;++j) sc[j]*=inv;
    }
    __syncthreads();
    if (tid < HD_) {
      const float* vp = kvm + (size_t)(b*10)*1536 + C_ + h*HD_ + tid;
      float acc = 0.f;
      for (int j=0;j<10;++j) acc += sc[j]*vp[(size_t)j*1536];
      qp[h*HD_+tid] = __float2bfloat16(acc);
    }
    __syncthreads();
  }
}

// ---- tgt init: mainx(BCHW->B,HW,C) + modality_query[0] + pos ----
__global__ void tgt0_kernel(const float* __restrict__ mainx, const float* __restrict__ mq,
                            const float* __restrict__ pos, float* __restrict__ tgt) {
  size_t i = (size_t)blockIdx.x*256 + threadIdx.x;
  if (i >= (size_t)TOK_*C_) return;
  int c = (int)(i % C_);
  size_t bt = i / C_;
  int tpos = (int)(bt % HW_);
  int b = (int)(bt / HW_);
  tgt[i] = mainx[((size_t)b*C_ + c)*HW_ + tpos] + mq[c] + pos[(size_t)tpos*C_ + c];
}

// ---- residual + layernorm (in place on fp32 tgt rows, bf16 add) ----
__global__ __launch_bounds__(256) void ln_res_kernel(float* __restrict__ tgt, const hbf16* __restrict__ add,
    const float* __restrict__ w, const float* __restrict__ bvec) {
  __shared__ float red[256];
  int row = blockIdx.x, tid = threadIdx.x;
  float* tp = tgt + (size_t)row*C_;
  const hbf16* ap = add + (size_t)row*C_;
  float x[3]; float s = 0.f, s2 = 0.f;
  #pragma unroll
  for (int i=0;i<3;++i){ int c=tid+i*256; float v=tp[c]+b2f(ap[c]); x[i]=v; s+=v; s2+=v*v; }
  s  = block_reduce_sum_256(s,  red);
  s2 = block_reduce_sum_256(s2, red);
  float mean = s * (1.f/C_);
  float var  = s2 * (1.f/C_) - mean*mean;
  float rstd = rsqrtf(var + 1e-5f);
  #pragma unroll
  for (int i=0;i<3;++i){ int c=tid+i*256; tp[c] = (x[i]-mean)*rstd*w[c] + bvec[c]; }
}

// ---- final transpose B,HW,C -> B,C,H,W ----
__global__ void out_kernel(const float* __restrict__ tgt, float* __restrict__ out) {
  size_t i = (size_t)blockIdx.x*256 + threadIdx.x;
  if (i >= (size_t)B_*C_*HW_) return;
  int wcol = (int)(i & 31);
  int hrow = (int)((i >> 5) & 31);
  size_t rest = i >> 10;
  int c = (int)(rest % C_);
  int b = (int)(rest / C_);
  out[i] = tgt[((size_t)b*HW_ + hrow*32 + wcol)*C_ + c];
}

extern "C" void kernel_launch(void* const* d_in, const int* in_sizes, int n_in,
                              void* d_out, int out_size, void* d_ws, size_t ws_size,
                              hipStream_t stream) {
  const float* mainx   = (const float*)d_in[0];
  const float* other[2]= {(const float*)d_in[1], (const float*)d_in[2]};
  const float* pos     = (const float*)d_in[3];
  const float* mq      = (const float*)d_in[4];
  const float* s_w1    = (const float*)d_in[5];
  const float* s_b1    = (const float*)d_in[6];
  const float* s_w2    = (const float*)d_in[7];
  const float* s_b2    = (const float*)d_in[8];
  const float* sa_in_w = (const float*)d_in[9];
  const float* sa_in_b = (const float*)d_in[10];
  const float* sa_out_w= (const float*)d_in[11];
  const float* sa_out_b= (const float*)d_in[12];
  const float* ca_in_w = (const float*)d_in[13];
  const float* ca_in_b = (const float*)d_in[14];
  const float* ca_out_w= (const float*)d_in[15];
  const float* ca_out_b= (const float*)d_in[16];
  const float* ff1_w   = (const float*)d_in[17];
  const float* ff1_b   = (const float*)d_in[18];
  const float* ff2_w   = (const float*)d_in[19];
  const float* ff2_b   = (const float*)d_in[20];
  const float* ln_w    = (const float*)d_in[21];
  const float* ln_b    = (const float*)d_in[22];
  const float* brand   = (const float*)d_in[23];
  const float* arand   = (const float*)d_in[24];

  // ---- workspace layout ----
  char* p = (char*)d_ws;
  auto alloc = [&](size_t bytes) { char* r = p; p += (bytes + 255) & ~(size_t)255; return (void*)r; };
  float* tgt    = (float*)alloc((size_t)TOK_*C_*4);       // 24 MB
  hbf16* wb0    = (hbf16*)alloc((size_t)2359296*2);       // 4.5 MB (max weight 3072x768)
  hbf16* wb1    = (hbf16*)alloc((size_t)2359296*2);       // 4.5 MB
  float* kvm    = (float*)alloc((size_t)80*1536*4);
  float* memf   = (float*)alloc((size_t)80*C_*4);
  float* coords = (float*)alloc((size_t)NPTS*2*4);
  float* score  = (float*)alloc((size_t)NPTS*4);
  int*   idxb   = (int*)alloc(64*4);
  char*  S      = p;
  size_t Savail = (ws_size > (size_t)(p - (char*)d_ws)) ? ws_size - (size_t)(p - (char*)d_ws) : 0;
  int CH = 1;
  if (Savail >= (size_t)8*1024*9216 + 4096) CH = 8;
  else if (Savail >= (size_t)4*1024*9216 + 4096) CH = 4;
  else if (Savail >= (size_t)2*1024*9216 + 4096) CH = 2;
  const size_t R = (size_t)CH*1024;

  // ---- stage A: per (modality, batch), fp32 exact (protects topk ordering) ----
  {
    float* pf   = (float*)S;                 // [2048,768]
    float* hbuf = pf + (size_t)NPTS*C_;      // [2048,768]
    for (int i = 0; i < 2; ++i) {
      for (int b = 0; b < B_; ++b) {
        sample_pf_kernel<<<NPTS, 256, 0, stream>>>(
            other[i] + (size_t)b*C_*HW_, brand + (size_t)(i*B_ + b)*4096, pf, coords);
        gemm_kernel<<<dim3(C_/BN, NPTS/BM), 256, 0, stream>>>(pf, C_, s_w1, C_, s_b1,
            hbuf, C_, NPTS, C_, C_, 1);
        score_reduce_kernel<<<NPTS, 256, 0, stream>>>(hbuf, s_w2, s_b2, score);
        topk_wave_kernel<<<1, 64, 0, stream>>>(score, idxb);
        softalign_kernel<<<TOPK_, 256, 0, stream>>>(mainx + (size_t)b*C_*HW_, pos, pf, coords,
            idxb, arand + (size_t)(i*B_ + b)*AROUND_*TOPK_*2, mq, i, memf + (size_t)b*MOD_*TOPK_*C_);
      }
    }
  }

  // ---- stage B ----
  size_t total = (size_t)TOK_*C_;
  tgt0_kernel<<<(int)((total+255)/256), 256, 0, stream>>>(mainx, mq, pos, tgt);

  for (int l = 0; l < 2; ++l) {
    // ===== self-attention =====
    f2b_kernel<<<(int)((C_*3*C_/4+255)/256), 256, 0, stream>>>(sa_in_w + (size_t)l*C_*3*C_, wb0, C_*3*C_);
    f2b_kernel<<<(int)((C_*C_/4+255)/256), 256, 0, stream>>>(sa_out_w + (size_t)l*C_*C_, wb1, C_*C_);
    for (int c0 = 0; c0 < B_; c0 += CH) {
      float* tgtc = tgt + (size_t)c0*HW_*C_;
      hbf16* abuf = (hbf16*)S;
      hbf16* qkv  = abuf + R*C_;
      hbf16* oatt = qkv + R*3*C_;
      hbf16* tmpb = oatt + R*C_;
      f2b_kernel<<<(int)((R*C_/4+255)/256), 256, 0, stream>>>(tgtc, abuf, (int)(R*C_));
      gemm_mfma<<<dim3(3*C_/128, (int)(R/128)), 256, 0, stream>>>((const short*)abuf, C_,
          (const short*)wb0, 3*C_, sa_in_b + (size_t)l*3*C_, qkv, 3*C_, C_, 0);
      for (int b = 0; b < CH; ++b)
        self_attn_kernel<<<NH_*HW_, 128, 0, stream>>>(qkv + (size_t)b*HW_*3*C_, oatt + (size_t)b*HW_*C_);
      gemm_mfma<<<dim3(C_/128, (int)(R/128)), 256, 0, stream>>>((const short*)oatt, C_,
          (const short*)wb1, C_, sa_out_b + (size_t)l*C_, tmpb, C_, C_, 0);
      ln_res_kernel<<<(int)R, 256, 0, stream>>>(tgtc, tmpb,
          ln_w + (size_t)(l*3+0)*C_, ln_b + (size_t)(l*3+0)*C_);
    }

    // ===== cross-attention =====
    f2b_kernel<<<(int)((C_*3*C_/4+255)/256), 256, 0, stream>>>(ca_in_w + (size_t)l*C_*3*C_, wb0, C_*3*C_);
    f2b_kernel<<<(int)((C_*C_/4+255)/256), 256, 0, stream>>>(ca_out_w + (size_t)l*C_*C_, wb1, C_*C_);
    gemm_kernel<<<dim3((2*C_+BN-1)/BN, (80+BM-1)/BM), 256, 0, stream>>>(memf, C_,
        ca_in_w + (size_t)l*C_*3*C_ + C_, 3*C_, ca_in_b + (size_t)l*3*C_ + C_, kvm, 2*C_,
        80, 2*C_, C_, 0);
    for (int c0 = 0; c0 < B_; c0 += CH) {
      float* tgtc = tgt + (size_t)c0*HW_*C_;
      hbf16* abuf = (hbf16*)S;
      hbf16* qb   = abuf + R*C_;
      hbf16* tmpb = qb + R*C_;
      f2b_kernel<<<(int)((R*C_/4+255)/256), 256, 0, stream>>>(tgtc, abuf, (int)(R*C_));
      gemm_mfma<<<dim3(C_/128, (int)(R/128)), 256, 0, stream>>>((const short*)abuf, C_,
          (const short*)wb0, 3*C_, ca_in_b + (size_t)l*3*C_, qb, C_, C_, 0);
      for (int b = 0; b < CH; ++b)
        cross_attn_kernel<<<HW_, 128, 0, stream>>>(qb + (size_t)b*HW_*C_, kvm, c0 + b);
      gemm_mfma<<<dim3(C_/128, (int)(R/128)), 256, 0, stream>>>((const short*)qb, C_,
          (const short*)wb1, C_, ca_out_b + (size_t)l*C_, tmpb, C_, C_, 0);
      ln_res_kernel<<<(int)R, 256, 0, stream>>>(tgtc, tmpb,
          ln_w + (size_t)(l*3+1)*C_, ln_b + (size_t)(l*3+1)*C_);
    }

    // ===== FFN =====
    f2b_kernel<<<(int)((C_*FF_/4+255)/256), 256, 0, stream>>>(ff1_w + (size_t)l*C_*FF_, wb0, C_*FF_);
    f2b_kernel<<<(int)((FF_*C_/4+255)/256), 256, 0, stream>>>(ff2_w + (size_t)l*FF_*C_, wb1, FF_*C_);
    for (int c0 = 0; c0 < B_; c0 += CH) {
      float* tgtc = tgt + (size_t)c0*HW_*C_;
      hbf16* abuf = (hbf16*)S;
      hbf16* ffh  = abuf + R*C_;
      hbf16* tmpb = ffh + R*FF_;
      f2b_kernel<<<(int)((R*C_/4+255)/256), 256, 0, stream>>>(tgtc, abuf, (int)(R*C_));
      gemm_mfma<<<dim3(FF_/128, (int)(R/128)), 256, 0, stream>>>((const short*)abuf, C_,
          (const short*)wb0, FF_, ff1_b + (size_t)l*FF_, ffh, FF_, C_, 1);
      gemm_mfma<<<dim3(C_/128, (int)(R/128)), 256, 0, stream>>>((const short*)ffh, FF_,
          (const short*)wb1, C_, ff2_b + (size_t)l*C_, tmpb, C_, FF_, 0);
      ln_res_kernel<<<(int)R, 256, 0, stream>>>(tgtc, tmpb,
          ln_w + (size_t)(l*3+2)*C_, ln_b + (size_t)(l*3+2)*C_);
    }
  }

  out_kernel<<<(int)((total+255)/256), 256, 0, stream>>>(tgt, (float*)d_out);
}

// Round 5
// 3362.491 us; speedup vs baseline: 5.0027x; 3.0362x over previous
//
#include <hip/hip_runtime.h>
#include <hip/hip_bf16.h>
#include <math.h>

typedef __hip_bfloat16 hbf16;

#define B_ 8
#define C_ 768
#define HW_ 1024
#define NH_ 8
#define HD_ 96
#define NPTS 2048      // PH*PW*K
#define AROUND_ 5
#define TOPK_ 5
#define MOD_ 2
#define FF_ 3072
#define TOK_ (B_*HW_)  // 8192

typedef __attribute__((ext_vector_type(8))) short short8v;
typedef __attribute__((ext_vector_type(4))) float f32x4;

__device__ __forceinline__ float b2f(hbf16 v){ return __bfloat162float(v); }

// ---- bilinear taps, torch grid_sample semantics (align_corners=False, zeros pad), H=W=32 ----
struct Taps { int x0,x1,y0,y1; float w00,w10,w01,w11; };
__device__ __forceinline__ Taps bilin_taps(float gx, float gy) {
  Taps t;
  float ix = ((gx+1.f)*32.f - 1.f)*0.5f;
  float iy = ((gy+1.f)*32.f - 1.f)*0.5f;
  float x0f = floorf(ix), y0f = floorf(iy);
  float wx1 = ix-x0f, wy1 = iy-y0f, wx0 = 1.f-wx1, wy0 = 1.f-wy1;
  int x0=(int)x0f, y0=(int)y0f, x1=x0+1, y1=y0+1;
  bool vx0=(x0>=0)&&(x0<=31), vx1=(x1>=0)&&(x1<=31);
  bool vy0=(y0>=0)&&(y0<=31), vy1=(y1>=0)&&(y1<=31);
  t.w00 = (vx0&&vy0) ? wx0*wy0 : 0.f;
  t.w10 = (vx1&&vy0) ? wx1*wy0 : 0.f;
  t.w01 = (vx0&&vy1) ? wx0*wy1 : 0.f;
  t.w11 = (vx1&&vy1) ? wx1*wy1 : 0.f;
  t.x0 = min(max(x0,0),31); t.x1 = min(max(x1,0),31);
  t.y0 = min(max(y0,0),31); t.y1 = min(max(y1,0),31);
  return t;
}

__device__ __forceinline__ float block_reduce_sum_256(float v, float* red) {
  int tid = threadIdx.x;
  red[tid] = v; __syncthreads();
  for (int s = 128; s > 0; s >>= 1) { if (tid < s) red[tid] += red[tid+s]; __syncthreads(); }
  float r = red[0]; __syncthreads();
  return r;
}

// ---- fp32 -> bf16 elementwise convert (n multiple of 4) ----
__global__ __launch_bounds__(256) void f2b_kernel(const float* __restrict__ in,
    hbf16* __restrict__ out, int n) {
  int i = (blockIdx.x*256 + threadIdx.x)*4;
  if (i >= n) return;
  float4 v = *(const float4*)&in[i];
  out[i+0] = __float2bfloat16(v.x);
  out[i+1] = __float2bfloat16(v.y);
  out[i+2] = __float2bfloat16(v.z);
  out[i+3] = __float2bfloat16(v.w);
}

// ---- stage A: blockwise sample for one (modality,batch) -> pf [NPTS,C], coords [NPTS,2] ----
__global__ __launch_bounds__(256) void sample_pf_kernel(const float* __restrict__ x,
    const float* __restrict__ brand, float* __restrict__ pf, float* __restrict__ coords) {
  int n = blockIdx.x;
  int k = n & 1, pw = (n >> 1) & 31, ph = n >> 6;
  int roff = ((ph*32 + pw)*2 + k)*2;
  float r0 = brand[roff], r1 = brand[roff+1];
  const float bs = 0.0625f;
  float c0 = r0*bs + ((float)ph*bs - 1.0f);
  float c1 = r1*bs + ((float)pw*bs - 1.0f);
  Taps t = bilin_taps(c0, c1);
  int i00=t.y0*32+t.x0, i10=t.y0*32+t.x1, i01=t.y1*32+t.x0, i11=t.y1*32+t.x1;
  float* pfo = pf + (size_t)n*C_;
  for (int c = threadIdx.x; c < C_; c += 256) {
    const float* xc = x + (size_t)c*HW_;
    pfo[c] = t.w00*xc[i00] + t.w10*xc[i10] + t.w01*xc[i01] + t.w11*xc[i11];
  }
  if (threadIdx.x == 0) { coords[n*2] = c0; coords[n*2+1] = c1; }
}

// ---- score tail: sigmoid(h . w2 + b2) per row ----
__global__ __launch_bounds__(256) void score_reduce_kernel(const float* __restrict__ h,
    const float* __restrict__ w2, const float* __restrict__ b2, float* __restrict__ score) {
  __shared__ float red[256];
  int row = blockIdx.x, tid = threadIdx.x;
  const float* hr = h + (size_t)row*C_;
  float s = hr[tid]*w2[tid] + hr[tid+256]*w2[tid+256] + hr[tid+512]*w2[tid+512];
  s = block_reduce_sum_256(s, red);
  if (tid == 0) score[row] = 1.f/(1.f+expf(-(s + b2[0])));
}

// ---- top-5 of 2048, jax.lax.top_k semantics (stable: ties keep smaller index) ----
__global__ void topk_wave_kernel(const float* __restrict__ score, int* __restrict__ idx) {
  int lane = threadIdx.x;   // 64 lanes, one wave
  float v[32];
  #pragma unroll
  for (int i = 0; i < 32; ++i) v[i] = score[(i<<6) | lane];
  for (int t = 0; t < TOPK_; ++t) {
    float bv = v[0]; int bi = lane;
    #pragma unroll
    for (int i = 1; i < 32; ++i) { if (v[i] > bv) { bv = v[i]; bi = (i<<6)|lane; } }
    for (int off = 32; off; off >>= 1) {
      float ov = __shfl_xor(bv, off);
      int   oi = __shfl_xor(bi, off);
      if (ov > bv || (ov == bv && oi < bi)) { bv = ov; bi = oi; }
    }
    if (lane == 0) idx[t] = bi;
    if ((bi & 63) == lane) v[bi >> 6] = -1e30f;
  }
}

// ---- soft_align + modality query -> memf rows, one block per t ----
__global__ __launch_bounds__(256) void softalign_kernel(const float* __restrict__ mainx_b,
    const float* __restrict__ pos, const float* __restrict__ pf, const float* __restrict__ coords,
    const int* __restrict__ idx, const float* __restrict__ arand_ib, const float* __restrict__ mq,
    int mod, float* __restrict__ memf_b) {
  int t = blockIdx.x;
  int tid = threadIdx.x;
  int n = idx[t];
  float px0 = coords[n*2], px1 = coords[n*2+1];
  const float* pfr = pf + (size_t)n*C_;
  float pfv[3];
  #pragma unroll
  for (int i=0;i<3;++i) pfv[i] = pfr[tid + i*256];
  __shared__ float red[256];
  float pp = block_reduce_sum_256(pfv[0]*pfv[0]+pfv[1]*pfv[1]+pfv[2]*pfv[2], red);
  float embr[AROUND_][3];
  float num_a[AROUND_], aa_a[AROUND_];
  for (int a=0; a<AROUND_; ++a) {
    int ar = (a*TOPK_ + t)*2;
    float g0 = px0 + (arand_ib[ar]*2.f - 0.5f)*0.2f;
    float g1 = px1 + (arand_ib[ar+1]*2.f - 0.5f)*0.2f;
    g0 = fminf(fmaxf(g0,-1.f),1.f);
    g1 = fminf(fmaxf(g1,-1.f),1.f);
    Taps tp = bilin_taps(g0, g1);
    int i00=tp.y0*32+tp.x0, i10=tp.y0*32+tp.x1, i01=tp.y1*32+tp.x0, i11=tp.y1*32+tp.x1;
    float s_num = 0.f, s_aa = 0.f;
    #pragma unroll
    for (int i=0;i<3;++i) {
      int c = tid + i*256;
      const float* mc = mainx_b + (size_t)c*HW_;
      float af = tp.w00*mc[i00] + tp.w10*mc[i10] + tp.w01*mc[i01] + tp.w11*mc[i11];
      float em = tp.w00*pos[(size_t)i00*C_+c] + tp.w10*pos[(size_t)i10*C_+c]
               + tp.w01*pos[(size_t)i01*C_+c] + tp.w11*pos[(size_t)i11*C_+c];
      embr[a][i] = em;
      s_num += pfv[i]*af;
      s_aa  += af*af;
    }
    num_a[a] = block_reduce_sum_256(s_num, red);
    aa_a[a]  = block_reduce_sum_256(s_aa, red);
  }
  float pn = fmaxf(sqrtf(pp), 1e-8f);
  float w[AROUND_]; float mx = -1e30f;
  #pragma unroll
  for (int a=0;a<AROUND_;++a){ float den = pn * fmaxf(sqrtf(aa_a[a]),1e-8f); w[a]=num_a[a]/den; mx=fmaxf(mx,w[a]); }
  float se = 0.f;
  #pragma unroll
  for (int a=0;a<AROUND_;++a){ w[a]=expf(w[a]-mx); se+=w[a]; }
  float inv = 1.f/se;
  float* mo = memf_b + (size_t)(mod*TOPK_ + t)*C_;
  #pragma unroll
  for (int i=0;i<3;++i) {
    int c = tid + i*256;
    float o = pfv[i];
    #pragma unroll
    for (int a=0;a<AROUND_;++a) o += embr[a][i]*(w[a]*inv);
    o += mq[(size_t)(mod+1)*C_ + c];
    mo[c] = o;
  }
}

// ---- generic fp32 GEMM (kept for score MLP + tiny kv GEMM) ----
#define BM 64
#define BN 64
#define BK 16
__global__ __launch_bounds__(256) void gemm_kernel(const float* __restrict__ A, int lda,
    const float* __restrict__ Bw, int ldb, const float* __restrict__ bias,
    float* __restrict__ Cm, int ldc, int M, int N, int K, int act) {
  __shared__ float As[BK][BM];
  __shared__ float Bs[BK][BN];
  int tid = threadIdx.x;
  int bm = blockIdx.y * BM, bn = blockIdx.x * BN;
  int arw = tid >> 2, acl = (tid & 3) << 2;
  int brw = tid >> 4, bcl = (tid & 15) << 2;
  int ty = tid >> 4, tx = tid & 15;
  float acc[4][4] = {{0.f}};
  for (int k0 = 0; k0 < K; k0 += BK) {
    float a0=0.f,a1=0.f,a2=0.f,a3=0.f;
    if (bm + arw < M) {
      const float* ap = A + (size_t)(bm+arw)*lda + k0 + acl;
      a0=ap[0]; a1=ap[1]; a2=ap[2]; a3=ap[3];
    }
    As[acl+0][arw]=a0; As[acl+1][arw]=a1; As[acl+2][arw]=a2; As[acl+3][arw]=a3;
    const float* bp = Bw + (size_t)(k0+brw)*ldb + bn + bcl;
    Bs[brw][bcl+0]=bp[0]; Bs[brw][bcl+1]=bp[1]; Bs[brw][bcl+2]=bp[2]; Bs[brw][bcl+3]=bp[3];
    __syncthreads();
    #pragma unroll
    for (int kk = 0; kk < BK; ++kk) {
      float4 av = *reinterpret_cast<const float4*>(&As[kk][ty<<2]);
      float4 bv = *reinterpret_cast<const float4*>(&Bs[kk][tx<<2]);
      acc[0][0]+=av.x*bv.x; acc[0][1]+=av.x*bv.y; acc[0][2]+=av.x*bv.z; acc[0][3]+=av.x*bv.w;
      acc[1][0]+=av.y*bv.x; acc[1][1]+=av.y*bv.y; acc[1][2]+=av.y*bv.z; acc[1][3]+=av.y*bv.w;
      acc[2][0]+=av.z*bv.x; acc[2][1]+=av.z*bv.y; acc[2][2]+=av.z*bv.z; acc[2][3]+=av.z*bv.w;
      acc[3][0]+=av.w*bv.x; acc[3][1]+=av.w*bv.y; acc[3][2]+=av.w*bv.z; acc[3][3]+=av.w*bv.w;
    }
    __syncthreads();
  }
  #pragma unroll
  for (int i=0;i<4;++i) {
    int r = bm + (ty<<2) + i;
    if (r >= M) continue;
    float* cp = Cm + (size_t)r*ldc + bn + (tx<<2);
    #pragma unroll
    for (int j=0;j<4;++j) {
      float v = acc[i][j] + bias[bn + (tx<<2) + j];
      if (act) v = fmaxf(v, 0.f);
      cp[j] = v;
    }
  }
}

// ---- bf16 MFMA GEMM: C[M,N] = act(A[M,K]bf16 @ B[K,N]bf16 + bias), 128x128 tile, BK=32 ----
__global__ __launch_bounds__(256) void gemm_mfma(const short* __restrict__ A, int lda,
    const short* __restrict__ Bw, int ldb, const float* __restrict__ bias,
    hbf16* __restrict__ Cm, int ldc, int K, int act) {
  __shared__ short As[128*40];
  __shared__ short Bs[128*40];
  int tid = threadIdx.x;
  int lane = tid & 63, w = tid >> 6;
  int wr = (w >> 1) * 64, wc = (w & 1) * 64;
  int m16 = lane & 15, q8 = (lane >> 4) * 8;
  int bm = blockIdx.y * 128, bn = blockIdx.x * 128;
  int ar = tid >> 2, ac = (tid & 3) * 8;
  int bnn = tid & 127, bkh = (tid >> 7) * 16;
  f32x4 acc[4][4] = {};
  for (int k0 = 0; k0 < K; k0 += 32) {
    *(short8v*)&As[ar*40 + ac]      = *(const short8v*)&A[(size_t)(bm+ar)*lda + k0 + ac];
    *(short8v*)&As[(ar+64)*40 + ac] = *(const short8v*)&A[(size_t)(bm+ar+64)*lda + k0 + ac];
    short bv[16];
    #pragma unroll
    for (int j = 0; j < 16; ++j) bv[j] = Bw[(size_t)(k0+bkh+j)*ldb + bn + bnn];
    *(short8v*)&Bs[bnn*40 + bkh]     = *(short8v*)&bv[0];
    *(short8v*)&Bs[bnn*40 + bkh + 8] = *(short8v*)&bv[8];
    __syncthreads();
    short8v af[4], bf[4];
    #pragma unroll
    for (int i=0;i<4;++i) af[i] = *(const short8v*)&As[(wr + i*16 + m16)*40 + q8];
    #pragma unroll
    for (int j=0;j<4;++j) bf[j] = *(const short8v*)&Bs[(wc + j*16 + m16)*40 + q8];
    #pragma unroll
    for (int i=0;i<4;++i)
      #pragma unroll
      for (int j=0;j<4;++j)
        acc[i][j] = __builtin_amdgcn_mfma_f32_16x16x32_bf16(af[i], bf[j], acc[i][j], 0, 0, 0);
    __syncthreads();
  }
  #pragma unroll
  for (int j=0;j<4;++j) {
    int col = bn + wc + j*16 + m16;
    float bs = bias[col];
    #pragma unroll
    for (int i=0;i<4;++i) {
      int row0 = bm + wr + i*16 + (lane>>4)*4;
      #pragma unroll
      for (int r=0;r<4;++r) {
        float v = acc[i][j][r] + bs;
        if (act) v = fmaxf(v, 0.f);
        Cm[(size_t)(row0+r)*ldc + col] = __float2bfloat16(v);
      }
    }
  }
}

// ---- fused flash self-attention (MFMA): grid (qtile=8, head=8, batch=CH), 256 thr ----
// qkv [batch][1024][2304] bf16 (Q|K|V each 768 = 8 heads x 96); o [batch][1024][768] bf16
__global__ __launch_bounds__(256) void flash_attn_kernel(const hbf16* __restrict__ qkv_all,
    hbf16* __restrict__ o_all) {
  const int q0 = blockIdx.x * 128;
  const int h  = blockIdx.y;
  const int bz = blockIdx.z;
  const short* qkv = (const short*)(qkv_all + (size_t)bz*HW_*2304);
  hbf16* ob = o_all + (size_t)bz*HW_*C_;
  const int tid = threadIdx.x;
  const int lane = tid & 63, w = tid >> 6;
  const int m16 = lane & 15, quad = lane >> 4, q8 = quad * 8;
  const float scale = 0.10206207261596577f;  // 1/sqrt(96)

  __shared__ short Qs[128*104];   // Q tile, row stride 104 (16B aligned, 2-way bank alias only)
  __shared__ short KP[128*72];    // K tile [64][104] (QK phase) aliased with P [128][72] (PV phase)
  __shared__ short Vt[96*72];     // V^T tile [d=96][j=64], stride 72

  // stage Q tile (128 rows x 96 d), 16B vector loads
  for (int idx = tid; idx < 128*12; idx += 256) {
    int row = idx / 12, dc = idx % 12;
    *(short8v*)&Qs[row*104 + dc*8] = *(const short8v*)&qkv[(size_t)(q0+row)*2304 + h*HD_ + dc*8];
  }

  float m_st[2][4], l_st[2][4];
  f32x4 o_acc[2][6] = {};
  #pragma unroll
  for (int i=0;i<2;++i)
    #pragma unroll
    for (int r=0;r<4;++r){ m_st[i][r] = -1e30f; l_st[i][r] = 0.f; }

  for (int t = 0; t < 16; ++t) {
    int j0 = t * 64;
    // stage K tile [64][104]
    for (int idx = tid; idx < 64*12; idx += 256) {
      int row = idx / 12, dc = idx % 12;
      *(short8v*)&KP[row*104 + dc*8] = *(const short8v*)&qkv[(size_t)(j0+row)*2304 + C_ + h*HD_ + dc*8];
    }
    // stage V^T tile: read V[j][d] vec8, scatter to Vt[d][j]
    for (int idx = tid; idx < 64*12; idx += 256) {
      int j = idx / 12, dc = idx % 12;
      short8v v = *(const short8v*)&qkv[(size_t)(j0+j)*2304 + 2*C_ + h*HD_ + dc*8];
      #pragma unroll
      for (int s = 0; s < 8; ++s) Vt[(dc*8+s)*72 + j] = v[s];
    }
    __syncthreads();

    // QK^T: each wave does 32 q-rows x 64 keys
    f32x4 accs[2][4] = {};
    #pragma unroll
    for (int kk = 0; kk < 96; kk += 32) {
      short8v af[2], bf[4];
      #pragma unroll
      for (int i=0;i<2;++i) af[i] = *(const short8v*)&Qs[(w*32 + i*16 + m16)*104 + q8 + kk];
      #pragma unroll
      for (int n=0;n<4;++n) bf[n] = *(const short8v*)&KP[(n*16 + m16)*104 + q8 + kk];
      #pragma unroll
      for (int i=0;i<2;++i)
        #pragma unroll
        for (int n=0;n<4;++n)
          accs[i][n] = __builtin_amdgcn_mfma_f32_16x16x32_bf16(af[i], bf[n], accs[i][n], 0, 0, 0);
    }
    __syncthreads();   // all QK reads of KP done before P overwrites it

    // online softmax + P write (wave-private rows of KP-as-P)
    #pragma unroll
    for (int i=0;i<2;++i) {
      #pragma unroll
      for (int r=0;r<4;++r) {
        float mx = -1e30f;
        #pragma unroll
        for (int n=0;n<4;++n) mx = fmaxf(mx, accs[i][n][r]*scale);
        #pragma unroll
        for (int off=1; off<16; off<<=1) mx = fmaxf(mx, __shfl_xor(mx, off));
        float m_new = fmaxf(m_st[i][r], mx);
        float alpha = expf(m_st[i][r] - m_new);
        float psum = 0.f;
        int prow = (w*32 + i*16 + quad*4 + r)*72 + m16;
        #pragma unroll
        for (int n=0;n<4;++n) {
          float pv = expf(accs[i][n][r]*scale - m_new);
          psum += pv;
          *(hbf16*)&KP[prow + n*16] = __float2bfloat16(pv);
        }
        #pragma unroll
        for (int off=1; off<16; off<<=1) psum += __shfl_xor(psum, off);
        l_st[i][r] = l_st[i][r]*alpha + psum;
        m_st[i][r] = m_new;
        #pragma unroll
        for (int dt=0; dt<6; ++dt) o_acc[i][dt][r] *= alpha;
      }
    }

    // PV: o_acc += P @ V  (P from own LDS rows, V^T from Vt)
    #pragma unroll
    for (int k0 = 0; k0 < 64; k0 += 32) {
      short8v pf_[2], vf[6];
      #pragma unroll
      for (int i=0;i<2;++i) pf_[i] = *(const short8v*)&KP[(w*32 + i*16 + m16)*72 + q8 + k0];
      #pragma unroll
      for (int dt=0; dt<6; ++dt) vf[dt] = *(const short8v*)&Vt[(dt*16 + m16)*72 + q8 + k0];
      #pragma unroll
      for (int i=0;i<2;++i)
        #pragma unroll
        for (int dt=0; dt<6; ++dt)
          o_acc[i][dt] = __builtin_amdgcn_mfma_f32_16x16x32_bf16(pf_[i], vf[dt], o_acc[i][dt], 0, 0, 0);
    }
    __syncthreads();   // before next tile restages KP/Vt
  }

  // epilogue: O row = o_acc / l
  #pragma unroll
  for (int i=0;i<2;++i) {
    #pragma unroll
    for (int r=0;r<4;++r) {
      float inv = 1.f / l_st[i][r];
      int row = q0 + w*32 + i*16 + quad*4 + r;
      #pragma unroll
      for (int dt=0; dt<6; ++dt)
        ob[(size_t)row*C_ + h*HD_ + dt*16 + m16] = __float2bfloat16(o_acc[i][dt][r]*inv);
    }
  }
}

// ---- cross-attention over 10 memory tokens for one batch, IN PLACE on bf16 q rows ----
__global__ __launch_bounds__(128) void cross_attn_kernel(hbf16* __restrict__ qb,
    const float* __restrict__ kvm, int b) {
  int gid = blockIdx.x;                  // row within batch
  int tid = threadIdx.x;
  __shared__ float sc[16];
  __shared__ float qs[C_];
  hbf16* qp = qb + (size_t)gid*C_;
  for (int c = tid; c < C_; c += 128) qs[c] = b2f(qp[c]);
  __syncthreads();
  const float scale = 0.10206207261596577f;
  for (int h = 0; h < NH_; ++h) {
    if (tid < 10) {
      const float* kp = kvm + (size_t)(b*10 + tid)*1536 + h*HD_;
      float s = 0.f;
      for (int d = 0; d < HD_; ++d) s += qs[h*HD_+d]*kp[d];
      sc[tid] = s*scale;
    }
    __syncthreads();
    if (tid == 0) {
      float m = -1e30f;
      for (int j=0;j<10;++j) m = fmaxf(m, sc[j]);
      float se = 0.f;
      for (int j=0;j<10;++j){ sc[j]=expf(sc[j]-m); se+=sc[j]; }
      float inv = 1.f/se;
      for (int j=0;j<10;++j) sc[j]*=inv;
    }
    __syncthreads();
    if (tid < HD_) {
      const float* vp = kvm + (size_t)(b*10)*1536 + C_ + h*HD_ + tid;
      float acc = 0.f;
      for (int j=0;j<10;++j) acc += sc[j]*vp[(size_t)j*1536];
      qp[h*HD_+tid] = __float2bfloat16(acc);
    }
    __syncthreads();
  }
}

// ---- tgt init: mainx(BCHW->B,HW,C) + modality_query[0] + pos ----
__global__ void tgt0_kernel(const float* __restrict__ mainx, const float* __restrict__ mq,
                            const float* __restrict__ pos, float* __restrict__ tgt) {
  size_t i = (size_t)blockIdx.x*256 + threadIdx.x;
  if (i >= (size_t)TOK_*C_) return;
  int c = (int)(i % C_);
  size_t bt = i / C_;
  int tpos = (int)(bt % HW_);
  int b = (int)(bt / HW_);
  tgt[i] = mainx[((size_t)b*C_ + c)*HW_ + tpos] + mq[c] + pos[(size_t)tpos*C_ + c];
}

// ---- residual + layernorm (in place on fp32 tgt rows, bf16 add) ----
__global__ __launch_bounds__(256) void ln_res_kernel(float* __restrict__ tgt, const hbf16* __restrict__ add,
    const float* __restrict__ w, const float* __restrict__ bvec) {
  __shared__ float red[256];
  int row = blockIdx.x, tid = threadIdx.x;
  float* tp = tgt + (size_t)row*C_;
  const hbf16* ap = add + (size_t)row*C_;
  float x[3]; float s = 0.f, s2 = 0.f;
  #pragma unroll
  for (int i=0;i<3;++i){ int c=tid+i*256; float v=tp[c]+b2f(ap[c]); x[i]=v; s+=v; s2+=v*v; }
  s  = block_reduce_sum_256(s,  red);
  s2 = block_reduce_sum_256(s2, red);
  float mean = s * (1.f/C_);
  float var  = s2 * (1.f/C_) - mean*mean;
  float rstd = rsqrtf(var + 1e-5f);
  #pragma unroll
  for (int i=0;i<3;++i){ int c=tid+i*256; tp[c] = (x[i]-mean)*rstd*w[c] + bvec[c]; }
}

// ---- final transpose B,HW,C -> B,C,H,W ----
__global__ void out_kernel(const float* __restrict__ tgt, float* __restrict__ out) {
  size_t i = (size_t)blockIdx.x*256 + threadIdx.x;
  if (i >= (size_t)B_*C_*HW_) return;
  int wcol = (int)(i & 31);
  int hrow = (int)((i >> 5) & 31);
  size_t rest = i >> 10;
  int c = (int)(rest % C_);
  int b = (int)(rest / C_);
  out[i] = tgt[((size_t)b*HW_ + hrow*32 + wcol)*C_ + c];
}

extern "C" void kernel_launch(void* const* d_in, const int* in_sizes, int n_in,
                              void* d_out, int out_size, void* d_ws, size_t ws_size,
                              hipStream_t stream) {
  const float* mainx   = (const float*)d_in[0];
  const float* other[2]= {(const float*)d_in[1], (const float*)d_in[2]};
  const float* pos     = (const float*)d_in[3];
  const float* mq      = (const float*)d_in[4];
  const float* s_w1    = (const float*)d_in[5];
  const float* s_b1    = (const float*)d_in[6];
  const float* s_w2    = (const float*)d_in[7];
  const float* s_b2    = (const float*)d_in[8];
  const float* sa_in_w = (const float*)d_in[9];
  const float* sa_in_b = (const float*)d_in[10];
  const float* sa_out_w= (const float*)d_in[11];
  const float* sa_out_b= (const float*)d_in[12];
  const float* ca_in_w = (const float*)d_in[13];
  const float* ca_in_b = (const float*)d_in[14];
  const float* ca_out_w= (const float*)d_in[15];
  const float* ca_out_b= (const float*)d_in[16];
  const float* ff1_w   = (const float*)d_in[17];
  const float* ff1_b   = (const float*)d_in[18];
  const float* ff2_w   = (const float*)d_in[19];
  const float* ff2_b   = (const float*)d_in[20];
  const float* ln_w    = (const float*)d_in[21];
  const float* ln_b    = (const float*)d_in[22];
  const float* brand   = (const float*)d_in[23];
  const float* arand   = (const float*)d_in[24];

  // ---- workspace layout ----
  char* p = (char*)d_ws;
  auto alloc = [&](size_t bytes) { char* r = p; p += (bytes + 255) & ~(size_t)255; return (void*)r; };
  float* tgt    = (float*)alloc((size_t)TOK_*C_*4);       // 24 MB
  hbf16* wb0    = (hbf16*)alloc((size_t)2359296*2);       // 4.5 MB
  hbf16* wb1    = (hbf16*)alloc((size_t)2359296*2);       // 4.5 MB
  float* kvm    = (float*)alloc((size_t)80*1536*4);
  float* memf   = (float*)alloc((size_t)80*C_*4);
  float* coords = (float*)alloc((size_t)NPTS*2*4);
  float* score  = (float*)alloc((size_t)NPTS*4);
  int*   idxb   = (int*)alloc(64*4);
  char*  S      = p;
  size_t Savail = (ws_size > (size_t)(p - (char*)d_ws)) ? ws_size - (size_t)(p - (char*)d_ws) : 0;
  int CH = 1;
  if (Savail >= (size_t)8*1024*9216 + 4096) CH = 8;
  else if (Savail >= (size_t)4*1024*9216 + 4096) CH = 4;
  else if (Savail >= (size_t)2*1024*9216 + 4096) CH = 2;
  const size_t R = (size_t)CH*1024;

  // ---- stage A: per (modality, batch), fp32 exact (protects topk ordering) ----
  {
    float* pf   = (float*)S;                 // [2048,768]
    float* hbuf = pf + (size_t)NPTS*C_;      // [2048,768]
    for (int i = 0; i < 2; ++i) {
      for (int b = 0; b < B_; ++b) {
        sample_pf_kernel<<<NPTS, 256, 0, stream>>>(
            other[i] + (size_t)b*C_*HW_, brand + (size_t)(i*B_ + b)*4096, pf, coords);
        gemm_kernel<<<dim3(C_/BN, NPTS/BM), 256, 0, stream>>>(pf, C_, s_w1, C_, s_b1,
            hbuf, C_, NPTS, C_, C_, 1);
        score_reduce_kernel<<<NPTS, 256, 0, stream>>>(hbuf, s_w2, s_b2, score);
        topk_wave_kernel<<<1, 64, 0, stream>>>(score, idxb);
        softalign_kernel<<<TOPK_, 256, 0, stream>>>(mainx + (size_t)b*C_*HW_, pos, pf, coords,
            idxb, arand + (size_t)(i*B_ + b)*AROUND_*TOPK_*2, mq, i, memf + (size_t)b*MOD_*TOPK_*C_);
      }
    }
  }

  // ---- stage B ----
  size_t total = (size_t)TOK_*C_;
  tgt0_kernel<<<(int)((total+255)/256), 256, 0, stream>>>(mainx, mq, pos, tgt);

  for (int l = 0; l < 2; ++l) {
    // ===== self-attention =====
    f2b_kernel<<<(int)((C_*3*C_/4+255)/256), 256, 0, stream>>>(sa_in_w + (size_t)l*C_*3*C_, wb0, C_*3*C_);
    f2b_kernel<<<(int)((C_*C_/4+255)/256), 256, 0, stream>>>(sa_out_w + (size_t)l*C_*C_, wb1, C_*C_);
    for (int c0 = 0; c0 < B_; c0 += CH) {
      float* tgtc = tgt + (size_t)c0*HW_*C_;
      hbf16* abuf = (hbf16*)S;
      hbf16* qkv  = abuf + R*C_;
      hbf16* oatt = qkv + R*3*C_;
      hbf16* tmpb = oatt + R*C_;
      f2b_kernel<<<(int)((R*C_/4+255)/256), 256, 0, stream>>>(tgtc, abuf, (int)(R*C_));
      gemm_mfma<<<dim3(3*C_/128, (int)(R/128)), 256, 0, stream>>>((const short*)abuf, C_,
          (const short*)wb0, 3*C_, sa_in_b + (size_t)l*3*C_, qkv, 3*C_, C_, 0);
      flash_attn_kernel<<<dim3(HW_/128, NH_, CH), 256, 0, stream>>>(qkv, oatt);
      gemm_mfma<<<dim3(C_/128, (int)(R/128)), 256, 0, stream>>>((const short*)oatt, C_,
          (const short*)wb1, C_, sa_out_b + (size_t)l*C_, tmpb, C_, C_, 0);
      ln_res_kernel<<<(int)R, 256, 0, stream>>>(tgtc, tmpb,
          ln_w + (size_t)(l*3+0)*C_, ln_b + (size_t)(l*3+0)*C_);
    }

    // ===== cross-attention =====
    f2b_kernel<<<(int)((C_*3*C_/4+255)/256), 256, 0, stream>>>(ca_in_w + (size_t)l*C_*3*C_, wb0, C_*3*C_);
    f2b_kernel<<<(int)((C_*C_/4+255)/256), 256, 0, stream>>>(ca_out_w + (size_t)l*C_*C_, wb1, C_*C_);
    gemm_kernel<<<dim3((2*C_+BN-1)/BN, (80+BM-1)/BM), 256, 0, stream>>>(memf, C_,
        ca_in_w + (size_t)l*C_*3*C_ + C_, 3*C_, ca_in_b + (size_t)l*3*C_ + C_, kvm, 2*C_,
        80, 2*C_, C_, 0);
    for (int c0 = 0; c0 < B_; c0 += CH) {
      float* tgtc = tgt + (size_t)c0*HW_*C_;
      hbf16* abuf = (hbf16*)S;
      hbf16* qb   = abuf + R*C_;
      hbf16* tmpb = qb + R*C_;
      f2b_kernel<<<(int)((R*C_/4+255)/256), 256, 0, stream>>>(tgtc, abuf, (int)(R*C_));
      gemm_mfma<<<dim3(C_/128, (int)(R/128)), 256, 0, stream>>>((const short*)abuf, C_,
          (const short*)wb0, 3*C_, ca_in_b + (size_t)l*3*C_, qb, C_, C_, 0);
      for (int b = 0; b < CH; ++b)
        cross_attn_kernel<<<HW_, 128, 0, stream>>>(qb + (size_t)b*HW_*C_, kvm, c0 + b);
      gemm_mfma<<<dim3(C_/128, (int)(R/128)), 256, 0, stream>>>((const short*)qb, C_,
          (const short*)wb1, C_, ca_out_b + (size_t)l*C_, tmpb, C_, C_, 0);
      ln_res_kernel<<<(int)R, 256, 0, stream>>>(tgtc, tmpb,
          ln_w + (size_t)(l*3+1)*C_, ln_b + (size_t)(l*3+1)*C_);
    }

    // ===== FFN =====
    f2b_kernel<<<(int)((C_*FF_/4+255)/256), 256, 0, stream>>>(ff1_w + (size_t)l*C_*FF_, wb0, C_*FF_);
    f2b_kernel<<<(int)((FF_*C_/4+255)/256), 256, 0, stream>>>(ff2_w + (size_t)l*FF_*C_, wb1, FF_*C_);
    for (int c0 = 0; c0 < B_; c0 += CH) {
      float* tgtc = tgt + (size_t)c0*HW_*C_;
      hbf16* abuf = (hbf16*)S;
      hbf16* ffh  = abuf + R*C_;
      hbf16* tmpb = ffh + R*FF_;
      f2b_kernel<<<(int)((R*C_/4+255)/256), 256, 0, stream>>>(tgtc, abuf, (int)(R*C_));
      gemm_mfma<<<dim3(FF_/128, (int)(R/128)), 256, 0, stream>>>((const short*)abuf, C_,
          (const short*)wb0, FF_, ff1_b + (size_t)l*FF_, ffh, FF_, C_, 1);
      gemm_mfma<<<dim3(C_/128, (int)(R/128)), 256, 0, stream>>>((const short*)ffh, FF_,
          (const short*)wb1, C_, ff2_b + (size_t)l*C_, tmpb, C_, FF_, 0);
      ln_res_kernel<<<(int)R, 256, 0, stream>>>(tgtc, tmpb,
          ln_w + (size_t)(l*3+2)*C_, ln_b + (size_t)(l*3+2)*C_);
    }
  }

  out_kernel<<<(int)((total+255)/256), 256, 0, stream>>>(tgt, (float*)d_out);
}

// Round 6
// 1898.964 us; speedup vs baseline: 8.8583x; 1.7707x over previous
//
#include <hip/hip_runtime.h>
#include <hip/hip_bf16.h>
#include <math.h>

typedef __hip_bfloat16 hbf16;

#define B_ 8
#define C_ 768
#define HW_ 1024
#define NH_ 8
#define HD_ 96
#define NPTS 2048      // PH*PW*K
#define AROUND_ 5
#define TOPK_ 5
#define MOD_ 2
#define FF_ 3072
#define TOK_ (B_*HW_)  // 8192

typedef __attribute__((ext_vector_type(8))) short short8v;
typedef __attribute__((ext_vector_type(4))) float f32x4;

__device__ __forceinline__ float b2f(hbf16 v){ return __bfloat162float(v); }

// ---- bilinear taps, torch grid_sample semantics (align_corners=False, zeros pad), H=W=32 ----
struct Taps { int x0,x1,y0,y1; float w00,w10,w01,w11; };
__device__ __forceinline__ Taps bilin_taps(float gx, float gy) {
  Taps t;
  float ix = ((gx+1.f)*32.f - 1.f)*0.5f;
  float iy = ((gy+1.f)*32.f - 1.f)*0.5f;
  float x0f = floorf(ix), y0f = floorf(iy);
  float wx1 = ix-x0f, wy1 = iy-y0f, wx0 = 1.f-wx1, wy0 = 1.f-wy1;
  int x0=(int)x0f, y0=(int)y0f, x1=x0+1, y1=y0+1;
  bool vx0=(x0>=0)&&(x0<=31), vx1=(x1>=0)&&(x1<=31);
  bool vy0=(y0>=0)&&(y0<=31), vy1=(y1>=0)&&(y1<=31);
  t.w00 = (vx0&&vy0) ? wx0*wy0 : 0.f;
  t.w10 = (vx1&&vy0) ? wx1*wy0 : 0.f;
  t.w01 = (vx0&&vy1) ? wx0*wy1 : 0.f;
  t.w11 = (vx1&&vy1) ? wx1*wy1 : 0.f;
  t.x0 = min(max(x0,0),31); t.x1 = min(max(x1,0),31);
  t.y0 = min(max(y0,0),31); t.y1 = min(max(y1,0),31);
  return t;
}

__device__ __forceinline__ float block_reduce_sum_256(float v, float* red) {
  int tid = threadIdx.x;
  red[tid] = v; __syncthreads();
  for (int s = 128; s > 0; s >>= 1) { if (tid < s) red[tid] += red[tid+s]; __syncthreads(); }
  float r = red[0]; __syncthreads();
  return r;
}

// ---- fp32 -> bf16 elementwise convert (n multiple of 4) ----
__global__ __launch_bounds__(256) void f2b_kernel(const float* __restrict__ in,
    hbf16* __restrict__ out, int n) {
  int i = (blockIdx.x*256 + threadIdx.x)*4;
  if (i >= n) return;
  float4 v = *(const float4*)&in[i];
  out[i+0] = __float2bfloat16(v.x);
  out[i+1] = __float2bfloat16(v.y);
  out[i+2] = __float2bfloat16(v.z);
  out[i+3] = __float2bfloat16(v.w);
}

// ---- transpose+convert: fp32 in[K][N] -> bf16 out[N][K] (K,N multiples of 32) ----
__global__ __launch_bounds__(256) void wtrans_kernel(const float* __restrict__ in,
    hbf16* __restrict__ out, int K, int N) {
  __shared__ float t[32][33];
  int tx = threadIdx.x & 31, ty = threadIdx.x >> 5;
  int k0 = blockIdx.y*32, n0 = blockIdx.x*32;
  #pragma unroll
  for (int i = 0; i < 32; i += 8) t[ty+i][tx] = in[(size_t)(k0+ty+i)*N + n0+tx];
  __syncthreads();
  #pragma unroll
  for (int i = 0; i < 32; i += 8)
    out[(size_t)(n0+ty+i)*K + k0 + tx] = __float2bfloat16(t[tx][ty+i]);
}

// ---- transpose + split-convert: fp32 in[K][N] -> hi[N][K], lo[N][K] ----
__global__ __launch_bounds__(256) void wtrans_split_kernel(const float* __restrict__ in,
    hbf16* __restrict__ hi, hbf16* __restrict__ lo, int K, int N) {
  __shared__ float t[32][33];
  int tx = threadIdx.x & 31, ty = threadIdx.x >> 5;
  int k0 = blockIdx.y*32, n0 = blockIdx.x*32;
  #pragma unroll
  for (int i = 0; i < 32; i += 8) t[ty+i][tx] = in[(size_t)(k0+ty+i)*N + n0+tx];
  __syncthreads();
  #pragma unroll
  for (int i = 0; i < 32; i += 8) {
    float v = t[tx][ty+i];
    hbf16 h = __float2bfloat16(v);
    hi[(size_t)(n0+ty+i)*K + k0 + tx] = h;
    lo[(size_t)(n0+ty+i)*K + k0 + tx] = __float2bfloat16(v - b2f(h));
  }
}

__global__ __launch_bounds__(256) void zero_kernel(float* __restrict__ p, int n) {
  int i = blockIdx.x*256 + threadIdx.x;
  if (i < n) p[i] = 0.f;
}

// ---- stage A: batched blockwise sample -> pf hi/lo [G][2048][768], coords [inst][2048][2] ----
__global__ __launch_bounds__(256) void sample_all_kernel(const float* __restrict__ other0,
    const float* __restrict__ other1, const float* __restrict__ brand,
    hbf16* __restrict__ pf_hi, hbf16* __restrict__ pf_lo, float* __restrict__ coords_all,
    int g0) {
  int ly = blockIdx.y;
  int inst = g0 + ly;
  int i = inst >> 3, b = inst & 7;
  const float* x = (i ? other1 : other0) + (size_t)b*C_*HW_;
  const float* br = brand + (size_t)inst*4096;
  int n = blockIdx.x;
  int k = n & 1, pw = (n >> 1) & 31, ph = n >> 6;
  int roff = ((ph*32 + pw)*2 + k)*2;
  float r0 = br[roff], r1 = br[roff+1];
  const float bs = 0.0625f;
  float c0 = r0*bs + ((float)ph*bs - 1.0f);
  float c1 = r1*bs + ((float)pw*bs - 1.0f);
  Taps t = bilin_taps(c0, c1);
  int i00=t.y0*32+t.x0, i10=t.y0*32+t.x1, i01=t.y1*32+t.x0, i11=t.y1*32+t.x1;
  size_t base = ((size_t)ly*NPTS + n)*C_;
  for (int c = threadIdx.x; c < C_; c += 256) {
    const float* xc = x + (size_t)c*HW_;
    float v = t.w00*xc[i00] + t.w10*xc[i10] + t.w01*xc[i01] + t.w11*xc[i11];
    hbf16 h = __float2bfloat16(v);
    pf_hi[base + c] = h;
    pf_lo[base + c] = __float2bfloat16(v - b2f(h));
  }
  if (threadIdx.x == 0) {
    size_t co = ((size_t)inst*NPTS + n)*2;
    coords_all[co] = c0; coords_all[co+1] = c1;
  }
}

// ---- fused score GEMM (split-bf16, 3-term) + relu + w2-dot -> atomicAdd logits ----
// grid (6, G*16); A split [M][768] k-contig; Bt split [768][768] n-rows k-contig
__global__ __launch_bounds__(256) void score_gemm_kernel(const short* __restrict__ Ahi,
    const short* __restrict__ Alo, const short* __restrict__ Bhi, const short* __restrict__ Blo,
    const float* __restrict__ b1, const float* __restrict__ w2, float* __restrict__ logit) {
  __shared__ short AsH[128*40];
  __shared__ short AsL[128*40];
  __shared__ short BsH[128*40];
  __shared__ short BsL[128*40];
  int tid = threadIdx.x;
  int lane = tid & 63, w = tid >> 6;
  int wr = (w >> 1) * 64, wc = (w & 1) * 64;
  int m16 = lane & 15, quad = lane >> 4, q8 = quad * 8;
  int bm = blockIdx.y * 128, bn = blockIdx.x * 128;
  int ar = tid >> 2, ac = (tid & 3) * 8;
  f32x4 acc[4][4] = {};
  for (int k0 = 0; k0 < 768; k0 += 32) {
    *(short8v*)&AsH[ar*40 + ac]      = *(const short8v*)&Ahi[(size_t)(bm+ar)*768 + k0 + ac];
    *(short8v*)&AsH[(ar+64)*40 + ac] = *(const short8v*)&Ahi[(size_t)(bm+ar+64)*768 + k0 + ac];
    *(short8v*)&AsL[ar*40 + ac]      = *(const short8v*)&Alo[(size_t)(bm+ar)*768 + k0 + ac];
    *(short8v*)&AsL[(ar+64)*40 + ac] = *(const short8v*)&Alo[(size_t)(bm+ar+64)*768 + k0 + ac];
    *(short8v*)&BsH[ar*40 + ac]      = *(const short8v*)&Bhi[(size_t)(bn+ar)*768 + k0 + ac];
    *(short8v*)&BsH[(ar+64)*40 + ac] = *(const short8v*)&Bhi[(size_t)(bn+ar+64)*768 + k0 + ac];
    *(short8v*)&BsL[ar*40 + ac]      = *(const short8v*)&Blo[(size_t)(bn+ar)*768 + k0 + ac];
    *(short8v*)&BsL[(ar+64)*40 + ac] = *(const short8v*)&Blo[(size_t)(bn+ar+64)*768 + k0 + ac];
    __syncthreads();
    short8v ah[4], al[4], bh[4], bl[4];
    #pragma unroll
    for (int i=0;i<4;++i) {
      ah[i] = *(const short8v*)&AsH[(wr + i*16 + m16)*40 + q8];
      al[i] = *(const short8v*)&AsL[(wr + i*16 + m16)*40 + q8];
      bh[i] = *(const short8v*)&BsH[(wc + i*16 + m16)*40 + q8];
      bl[i] = *(const short8v*)&BsL[(wc + i*16 + m16)*40 + q8];
    }
    #pragma unroll
    for (int i=0;i<4;++i)
      #pragma unroll
      for (int j=0;j<4;++j) {
        acc[i][j] = __builtin_amdgcn_mfma_f32_16x16x32_bf16(ah[i], bh[j], acc[i][j], 0, 0, 0);
        acc[i][j] = __builtin_amdgcn_mfma_f32_16x16x32_bf16(ah[i], bl[j], acc[i][j], 0, 0, 0);
        acc[i][j] = __builtin_amdgcn_mfma_f32_16x16x32_bf16(al[i], bh[j], acc[i][j], 0, 0, 0);
      }
    __syncthreads();
  }
  float b1v[4], w2v[4];
  #pragma unroll
  for (int j=0;j<4;++j) {
    int col = bn + wc + j*16 + m16;
    b1v[j] = b1[col]; w2v[j] = w2[col];
  }
  #pragma unroll
  for (int i=0;i<4;++i) {
    #pragma unroll
    for (int r=0;r<4;++r) {
      float v = 0.f;
      #pragma unroll
      for (int j=0;j<4;++j) {
        float h = fmaxf(acc[i][j][r] + b1v[j], 0.f);
        v += h * w2v[j];
      }
      v += __shfl_xor(v, 1); v += __shfl_xor(v, 2);
      v += __shfl_xor(v, 4); v += __shfl_xor(v, 8);
      if (m16 == 0) atomicAdd(&logit[bm + wr + i*16 + quad*4 + r], v);
    }
  }
}

// ---- top-5 of 2048 per instance (on logits; sigmoid monotone), jax tie semantics ----
__global__ void topk_all_kernel(const float* __restrict__ logit, int* __restrict__ idx) {
  int lane = threadIdx.x;   // 64 lanes
  const float* score = logit + (size_t)blockIdx.x*NPTS;
  float v[32];
  #pragma unroll
  for (int i = 0; i < 32; ++i) v[i] = score[(i<<6) | lane];
  for (int t = 0; t < TOPK_; ++t) {
    float bv = v[0]; int bi = lane;
    #pragma unroll
    for (int i = 1; i < 32; ++i) { if (v[i] > bv) { bv = v[i]; bi = (i<<6)|lane; } }
    for (int off = 32; off; off >>= 1) {
      float ov = __shfl_xor(bv, off);
      int   oi = __shfl_xor(bi, off);
      if (ov > bv || (ov == bv && oi < bi)) { bv = ov; bi = oi; }
    }
    if (lane == 0) idx[blockIdx.x*8 + t] = bi;
    if ((bi & 63) == lane) v[bi >> 6] = -1e30f;
  }
}

// ---- soft_align + modality query -> memf rows; grid (TOPK, G) ----
__global__ __launch_bounds__(256) void softalign_all_kernel(const float* __restrict__ mainx,
    const float* __restrict__ pos, const hbf16* __restrict__ pf_hi, const hbf16* __restrict__ pf_lo,
    const float* __restrict__ coords_all, const int* __restrict__ idx_all,
    const float* __restrict__ arand, const float* __restrict__ mq,
    float* __restrict__ memf, int g0) {
  int t = blockIdx.x;
  int ly = blockIdx.y;
  int inst = g0 + ly;
  int mod = inst >> 3, b = inst & 7;
  const float* mainx_b = mainx + (size_t)b*C_*HW_;
  const float* arand_ib = arand + (size_t)inst*AROUND_*TOPK_*2;
  const float* coords = coords_all + (size_t)inst*NPTS*2;
  int tid = threadIdx.x;
  int n = idx_all[ly*8 + t];
  float px0 = coords[n*2], px1 = coords[n*2+1];
  size_t pfb = ((size_t)ly*NPTS + n)*C_;
  float pfv[3];
  #pragma unroll
  for (int i=0;i<3;++i) {
    int c = tid + i*256;
    pfv[i] = b2f(pf_hi[pfb + c]) + b2f(pf_lo[pfb + c]);
  }
  __shared__ float red[256];
  float pp = block_reduce_sum_256(pfv[0]*pfv[0]+pfv[1]*pfv[1]+pfv[2]*pfv[2], red);
  float embr[AROUND_][3];
  float num_a[AROUND_], aa_a[AROUND_];
  for (int a=0; a<AROUND_; ++a) {
    int ar = (a*TOPK_ + t)*2;
    float g0c = px0 + (arand_ib[ar]*2.f - 0.5f)*0.2f;
    float g1c = px1 + (arand_ib[ar+1]*2.f - 0.5f)*0.2f;
    g0c = fminf(fmaxf(g0c,-1.f),1.f);
    g1c = fminf(fmaxf(g1c,-1.f),1.f);
    Taps tp = bilin_taps(g0c, g1c);
    int i00=tp.y0*32+tp.x0, i10=tp.y0*32+tp.x1, i01=tp.y1*32+tp.x0, i11=tp.y1*32+tp.x1;
    float s_num = 0.f, s_aa = 0.f;
    #pragma unroll
    for (int i=0;i<3;++i) {
      int c = tid + i*256;
      const float* mc = mainx_b + (size_t)c*HW_;
      float af = tp.w00*mc[i00] + tp.w10*mc[i10] + tp.w01*mc[i01] + tp.w11*mc[i11];
      float em = tp.w00*pos[(size_t)i00*C_+c] + tp.w10*pos[(size_t)i10*C_+c]
               + tp.w01*pos[(size_t)i01*C_+c] + tp.w11*pos[(size_t)i11*C_+c];
      embr[a][i] = em;
      s_num += pfv[i]*af;
      s_aa  += af*af;
    }
    num_a[a] = block_reduce_sum_256(s_num, red);
    aa_a[a]  = block_reduce_sum_256(s_aa, red);
  }
  float pn = fmaxf(sqrtf(pp), 1e-8f);
  float w[AROUND_]; float mx = -1e30f;
  #pragma unroll
  for (int a=0;a<AROUND_;++a){ float den = pn * fmaxf(sqrtf(aa_a[a]),1e-8f); w[a]=num_a[a]/den; mx=fmaxf(mx,w[a]); }
  float se = 0.f;
  #pragma unroll
  for (int a=0;a<AROUND_;++a){ w[a]=expf(w[a]-mx); se+=w[a]; }
  float inv = 1.f/se;
  float* mo = memf + ((size_t)b*(MOD_*TOPK_) + mod*TOPK_ + t)*C_;
  #pragma unroll
  for (int i=0;i<3;++i) {
    int c = tid + i*256;
    float o = pfv[i];
    #pragma unroll
    for (int a=0;a<AROUND_;++a) o += embr[a][i]*(w[a]*inv);
    o += mq[(size_t)(mod+1)*C_ + c];
    mo[c] = o;
  }
}

// ---- generic fp32 GEMM (kvm only) ----
#define BM 64
#define BN 64
#define BK 16
__global__ __launch_bounds__(256) void gemm_kernel(const float* __restrict__ A, int lda,
    const float* __restrict__ Bw, int ldb, const float* __restrict__ bias,
    float* __restrict__ Cm, int ldc, int M, int N, int K, int act) {
  __shared__ float As[BK][BM];
  __shared__ float Bs[BK][BN];
  int tid = threadIdx.x;
  int bm = blockIdx.y * BM, bn = blockIdx.x * BN;
  int arw = tid >> 2, acl = (tid & 3) << 2;
  int brw = tid >> 4, bcl = (tid & 15) << 2;
  int ty = tid >> 4, tx = tid & 15;
  float acc[4][4] = {{0.f}};
  for (int k0 = 0; k0 < K; k0 += BK) {
    float a0=0.f,a1=0.f,a2=0.f,a3=0.f;
    if (bm + arw < M) {
      const float* ap = A + (size_t)(bm+arw)*lda + k0 + acl;
      a0=ap[0]; a1=ap[1]; a2=ap[2]; a3=ap[3];
    }
    As[acl+0][arw]=a0; As[acl+1][arw]=a1; As[acl+2][arw]=a2; As[acl+3][arw]=a3;
    const float* bp = Bw + (size_t)(k0+brw)*ldb + bn + bcl;
    Bs[brw][bcl+0]=bp[0]; Bs[brw][bcl+1]=bp[1]; Bs[brw][bcl+2]=bp[2]; Bs[brw][bcl+3]=bp[3];
    __syncthreads();
    #pragma unroll
    for (int kk = 0; kk < BK; ++kk) {
      float4 av = *reinterpret_cast<const float4*>(&As[kk][ty<<2]);
      float4 bv = *reinterpret_cast<const float4*>(&Bs[kk][tx<<2]);
      acc[0][0]+=av.x*bv.x; acc[0][1]+=av.x*bv.y; acc[0][2]+=av.x*bv.z; acc[0][3]+=av.x*bv.w;
      acc[1][0]+=av.y*bv.x; acc[1][1]+=av.y*bv.y; acc[1][2]+=av.y*bv.z; acc[1][3]+=av.y*bv.w;
      acc[2][0]+=av.z*bv.x; acc[2][1]+=av.z*bv.y; acc[2][2]+=av.z*bv.z; acc[2][3]+=av.z*bv.w;
      acc[3][0]+=av.w*bv.x; acc[3][1]+=av.w*bv.y; acc[3][2]+=av.w*bv.z; acc[3][3]+=av.w*bv.w;
    }
    __syncthreads();
  }
  #pragma unroll
  for (int i=0;i<4;++i) {
    int r = bm + (ty<<2) + i;
    if (r >= M) continue;
    float* cp = Cm + (size_t)r*ldc + bn + (tx<<2);
    #pragma unroll
    for (int j=0;j<4;++j) {
      float v = acc[i][j] + bias[bn + (tx<<2) + j];
      if (act) v = fmaxf(v, 0.f);
      cp[j] = v;
    }
  }
}

// ---- bf16 MFMA GEMM, B pre-transposed: C = act(A[M,K] @ Bt[N,K]^T + bias) ----
__global__ __launch_bounds__(256) void gemm_mfma_t(const short* __restrict__ A, int lda,
    const short* __restrict__ Bt, int ldbt, const float* __restrict__ bias,
    hbf16* __restrict__ Cm, int ldc, int K, int act) {
  __shared__ short As[128*40];
  __shared__ short Bs[128*40];
  int tid = threadIdx.x;
  int lane = tid & 63, w = tid >> 6;
  int wr = (w >> 1) * 64, wc = (w & 1) * 64;
  int m16 = lane & 15, q8 = (lane >> 4) * 8;
  int bm = blockIdx.y * 128, bn = blockIdx.x * 128;
  int ar = tid >> 2, ac = (tid & 3) * 8;
  f32x4 acc[4][4] = {};
  for (int k0 = 0; k0 < K; k0 += 32) {
    *(short8v*)&As[ar*40 + ac]      = *(const short8v*)&A[(size_t)(bm+ar)*lda + k0 + ac];
    *(short8v*)&As[(ar+64)*40 + ac] = *(const short8v*)&A[(size_t)(bm+ar+64)*lda + k0 + ac];
    *(short8v*)&Bs[ar*40 + ac]      = *(const short8v*)&Bt[(size_t)(bn+ar)*ldbt + k0 + ac];
    *(short8v*)&Bs[(ar+64)*40 + ac] = *(const short8v*)&Bt[(size_t)(bn+ar+64)*ldbt + k0 + ac];
    __syncthreads();
    short8v af[4], bf[4];
    #pragma unroll
    for (int i=0;i<4;++i) af[i] = *(const short8v*)&As[(wr + i*16 + m16)*40 + q8];
    #pragma unroll
    for (int j=0;j<4;++j) bf[j] = *(const short8v*)&Bs[(wc + j*16 + m16)*40 + q8];
    #pragma unroll
    for (int i=0;i<4;++i)
      #pragma unroll
      for (int j=0;j<4;++j)
        acc[i][j] = __builtin_amdgcn_mfma_f32_16x16x32_bf16(af[i], bf[j], acc[i][j], 0, 0, 0);
    __syncthreads();
  }
  #pragma unroll
  for (int j=0;j<4;++j) {
    int col = bn + wc + j*16 + m16;
    float bs = bias[col];
    #pragma unroll
    for (int i=0;i<4;++i) {
      int row0 = bm + wr + i*16 + (lane>>4)*4;
      #pragma unroll
      for (int r=0;r<4;++r) {
        float v = acc[i][j][r] + bs;
        if (act) v = fmaxf(v, 0.f);
        Cm[(size_t)(row0+r)*ldc + col] = __float2bfloat16(v);
      }
    }
  }
}

// ---- fused flash self-attention (MFMA): grid (qtile=8, head=8, batch=CH), 256 thr ----
__global__ __launch_bounds__(256) void flash_attn_kernel(const hbf16* __restrict__ qkv_all,
    hbf16* __restrict__ o_all) {
  const int q0 = blockIdx.x * 128;
  const int h  = blockIdx.y;
  const int bz = blockIdx.z;
  const short* qkv = (const short*)(qkv_all + (size_t)bz*HW_*2304);
  hbf16* ob = o_all + (size_t)bz*HW_*C_;
  const int tid = threadIdx.x;
  const int lane = tid & 63, w = tid >> 6;
  const int m16 = lane & 15, quad = lane >> 4, q8 = quad * 8;
  const float scale = 0.10206207261596577f;  // 1/sqrt(96)

  __shared__ short Qs[128*104];
  __shared__ short KP[128*72];    // K tile [64][104] (QK) aliased with P [128][72] (PV)
  __shared__ short Vt[96*72];     // V^T tile [d][j]

  for (int idx = tid; idx < 128*12; idx += 256) {
    int row = idx / 12, dc = idx % 12;
    *(short8v*)&Qs[row*104 + dc*8] = *(const short8v*)&qkv[(size_t)(q0+row)*2304 + h*HD_ + dc*8];
  }

  float m_st[2][4], l_st[2][4];
  f32x4 o_acc[2][6] = {};
  #pragma unroll
  for (int i=0;i<2;++i)
    #pragma unroll
    for (int r=0;r<4;++r){ m_st[i][r] = -1e30f; l_st[i][r] = 0.f; }

  for (int t = 0; t < 16; ++t) {
    int j0 = t * 64;
    for (int idx = tid; idx < 64*12; idx += 256) {
      int row = idx / 12, dc = idx % 12;
      *(short8v*)&KP[row*104 + dc*8] = *(const short8v*)&qkv[(size_t)(j0+row)*2304 + C_ + h*HD_ + dc*8];
    }
    // V^T stage: j fast within wave -> conflict-free LDS writes
    for (int idx = tid; idx < 64*12; idx += 256) {
      int j = idx & 63, dc = idx >> 6;
      short8v v = *(const short8v*)&qkv[(size_t)(j0+j)*2304 + 2*C_ + h*HD_ + dc*8];
      #pragma unroll
      for (int s = 0; s < 8; ++s) Vt[(dc*8+s)*72 + j] = v[s];
    }
    __syncthreads();

    f32x4 accs[2][4] = {};
    #pragma unroll
    for (int kk = 0; kk < 96; kk += 32) {
      short8v af[2], bf[4];
      #pragma unroll
      for (int i=0;i<2;++i) af[i] = *(const short8v*)&Qs[(w*32 + i*16 + m16)*104 + q8 + kk];
      #pragma unroll
      for (int n=0;n<4;++n) bf[n] = *(const short8v*)&KP[(n*16 + m16)*104 + q8 + kk];
      #pragma unroll
      for (int i=0;i<2;++i)
        #pragma unroll
        for (int n=0;n<4;++n)
          accs[i][n] = __builtin_amdgcn_mfma_f32_16x16x32_bf16(af[i], bf[n], accs[i][n], 0, 0, 0);
    }
    __syncthreads();

    #pragma unroll
    for (int i=0;i<2;++i) {
      #pragma unroll
      for (int r=0;r<4;++r) {
        float mx = -1e30f;
        #pragma unroll
        for (int n=0;n<4;++n) mx = fmaxf(mx, accs[i][n][r]*scale);
        #pragma unroll
        for (int off=1; off<16; off<<=1) mx = fmaxf(mx, __shfl_xor(mx, off));
        float m_new = fmaxf(m_st[i][r], mx);
        float alpha = expf(m_st[i][r] - m_new);
        float psum = 0.f;
        int prow = (w*32 + i*16 + quad*4 + r)*72 + m16;
        #pragma unroll
        for (int n=0;n<4;++n) {
          float pv = expf(accs[i][n][r]*scale - m_new);
          psum += pv;
          *(hbf16*)&KP[prow + n*16] = __float2bfloat16(pv);
        }
        #pragma unroll
        for (int off=1; off<16; off<<=1) psum += __shfl_xor(psum, off);
        l_st[i][r] = l_st[i][r]*alpha + psum;
        m_st[i][r] = m_new;
        #pragma unroll
        for (int dt=0; dt<6; ++dt) o_acc[i][dt][r] *= alpha;
      }
    }

    #pragma unroll
    for (int k0 = 0; k0 < 64; k0 += 32) {
      short8v pf_[2], vf[6];
      #pragma unroll
      for (int i=0;i<2;++i) pf_[i] = *(const short8v*)&KP[(w*32 + i*16 + m16)*72 + q8 + k0];
      #pragma unroll
      for (int dt=0; dt<6; ++dt) vf[dt] = *(const short8v*)&Vt[(dt*16 + m16)*72 + q8 + k0];
      #pragma unroll
      for (int i=0;i<2;++i)
        #pragma unroll
        for (int dt=0; dt<6; ++dt)
          o_acc[i][dt] = __builtin_amdgcn_mfma_f32_16x16x32_bf16(pf_[i], vf[dt], o_acc[i][dt], 0, 0, 0);
    }
    __syncthreads();
  }

  #pragma unroll
  for (int i=0;i<2;++i) {
    #pragma unroll
    for (int r=0;r<4;++r) {
      float inv = 1.f / l_st[i][r];
      int row = q0 + w*32 + i*16 + quad*4 + r;
      #pragma unroll
      for (int dt=0; dt<6; ++dt)
        ob[(size_t)row*C_ + h*HD_ + dt*16 + m16] = __float2bfloat16(o_acc[i][dt][r]*inv);
    }
  }
}

// ---- cross-attention over 10 memory tokens, grid (1024, CH), IN PLACE on bf16 q rows ----
__global__ __launch_bounds__(128) void cross_attn_kernel(hbf16* __restrict__ qb,
    const float* __restrict__ kvm, int b0) {
  int row = blockIdx.x;
  int lb = blockIdx.y;
  int b = b0 + lb;
  int tid = threadIdx.x;
  __shared__ float sc[16];
  __shared__ float qs[C_];
  hbf16* qp = qb + ((size_t)lb*HW_ + row)*C_;
  for (int c = tid; c < C_; c += 128) qs[c] = b2f(qp[c]);
  __syncthreads();
  const float scale = 0.10206207261596577f;
  for (int h = 0; h < NH_; ++h) {
    if (tid < 10) {
      const float* kp = kvm + (size_t)(b*10 + tid)*1536 + h*HD_;
      float s = 0.f;
      for (int d = 0; d < HD_; ++d) s += qs[h*HD_+d]*kp[d];
      sc[tid] = s*scale;
    }
    __syncthreads();
    if (tid == 0) {
      float m = -1e30f;
      for (int j=0;j<10;++j) m = fmaxf(m, sc[j]);
      float se = 0.f;
      for (int j=0;j<10;++j){ sc[j]=expf(sc[j]-m); se+=sc[j]; }
      float inv = 1.f/se;
      for (int j=0;j<10;++j) sc[j]*=inv;
    }
    __syncthreads();
    if (tid < HD_) {
      const float* vp = kvm + (size_t)(b*10)*1536 + C_ + h*HD_ + tid;
      float acc = 0.f;
      for (int j=0;j<10;++j) acc += sc[j]*vp[(size_t)j*1536];
      qp[h*HD_+tid] = __float2bfloat16(acc);
    }
    __syncthreads();
  }
}

// ---- tgt init: mainx(BCHW->B,HW,C) + modality_query[0] + pos ----
__global__ void tgt0_kernel(const float* __restrict__ mainx, const float* __restrict__ mq,
                            const float* __restrict__ pos, float* __restrict__ tgt) {
  size_t i = (size_t)blockIdx.x*256 + threadIdx.x;
  if (i >= (size_t)TOK_*C_) return;
  int c = (int)(i % C_);
  size_t bt = i / C_;
  int tpos = (int)(bt % HW_);
  int b = (int)(bt / HW_);
  tgt[i] = mainx[((size_t)b*C_ + c)*HW_ + tpos] + mq[c] + pos[(size_t)tpos*C_ + c];
}

// ---- residual + layernorm (in place on fp32 tgt rows, bf16 add) ----
__global__ __launch_bounds__(256) void ln_res_kernel(float* __restrict__ tgt, const hbf16* __restrict__ add,
    const float* __restrict__ w, const float* __restrict__ bvec) {
  __shared__ float red[256];
  int row = blockIdx.x, tid = threadIdx.x;
  float* tp = tgt + (size_t)row*C_;
  const hbf16* ap = add + (size_t)row*C_;
  float x[3]; float s = 0.f, s2 = 0.f;
  #pragma unroll
  for (int i=0;i<3;++i){ int c=tid+i*256; float v=tp[c]+b2f(ap[c]); x[i]=v; s+=v; s2+=v*v; }
  s  = block_reduce_sum_256(s,  red);
  s2 = block_reduce_sum_256(s2, red);
  float mean = s * (1.f/C_);
  float var  = s2 * (1.f/C_) - mean*mean;
  float rstd = rsqrtf(var + 1e-5f);
  #pragma unroll
  for (int i=0;i<3;++i){ int c=tid+i*256; tp[c] = (x[i]-mean)*rstd*w[c] + bvec[c]; }
}

// ---- final transpose B,HW,C -> B,C,H,W ----
__global__ void out_kernel(const float* __restrict__ tgt, float* __restrict__ out) {
  size_t i = (size_t)blockIdx.x*256 + threadIdx.x;
  if (i >= (size_t)B_*C_*HW_) return;
  int wcol = (int)(i & 31);
  int hrow = (int)((i >> 5) & 31);
  size_t rest = i >> 10;
  int c = (int)(rest % C_);
  int b = (int)(rest / C_);
  out[i] = tgt[((size_t)b*HW_ + hrow*32 + wcol)*C_ + c];
}

extern "C" void kernel_launch(void* const* d_in, const int* in_sizes, int n_in,
                              void* d_out, int out_size, void* d_ws, size_t ws_size,
                              hipStream_t stream) {
  const float* mainx   = (const float*)d_in[0];
  const float* other0  = (const float*)d_in[1];
  const float* other1  = (const float*)d_in[2];
  const float* pos     = (const float*)d_in[3];
  const float* mq      = (const float*)d_in[4];
  const float* s_w1    = (const float*)d_in[5];
  const float* s_b1    = (const float*)d_in[6];
  const float* s_w2    = (const float*)d_in[7];
  const float* sa_in_w = (const float*)d_in[9];
  const float* sa_in_b = (const float*)d_in[10];
  const float* sa_out_w= (const float*)d_in[11];
  const float* sa_out_b= (const float*)d_in[12];
  const float* ca_in_w = (const float*)d_in[13];
  const float* ca_in_b = (const float*)d_in[14];
  const float* ca_out_w= (const float*)d_in[15];
  const float* ca_out_b= (const float*)d_in[16];
  const float* ff1_w   = (const float*)d_in[17];
  const float* ff1_b   = (const float*)d_in[18];
  const float* ff2_w   = (const float*)d_in[19];
  const float* ff2_b   = (const float*)d_in[20];
  const float* ln_w    = (const float*)d_in[21];
  const float* ln_b    = (const float*)d_in[22];
  const float* brand   = (const float*)d_in[23];
  const float* arand   = (const float*)d_in[24];

  // ---- workspace layout ----
  char* p = (char*)d_ws;
  auto alloc = [&](size_t bytes) { char* r = p; p += (bytes + 255) & ~(size_t)255; return (void*)r; };
  float* tgt    = (float*)alloc((size_t)TOK_*C_*4);       // 24 MB
  hbf16* wb0    = (hbf16*)alloc((size_t)2359296*2);       // 4.5 MB (transposed weights)
  hbf16* wb1    = (hbf16*)alloc((size_t)2359296*2);       // 4.5 MB
  hbf16* w1t_hi = (hbf16*)alloc((size_t)C_*C_*2);
  hbf16* w1t_lo = (hbf16*)alloc((size_t)C_*C_*2);
  float* kvm    = (float*)alloc((size_t)80*1536*4);
  float* memf   = (float*)alloc((size_t)80*C_*4);
  float* coords = (float*)alloc((size_t)16*NPTS*2*4);
  float* logit  = (float*)alloc((size_t)16*NPTS*4);
  int*   idxb   = (int*)alloc(16*8*4);
  char*  S      = p;
  size_t used = (size_t)(p - (char*)d_ws);
  size_t Savail = (ws_size > used) ? ws_size - used : 0;
  int CH = 1;
  if (Savail >= (size_t)8*1024*9216 + 4096) CH = 8;
  else if (Savail >= (size_t)4*1024*9216 + 4096) CH = 4;
  else if (Savail >= (size_t)2*1024*9216 + 4096) CH = 2;
  const size_t R = (size_t)CH*1024;
  const size_t perG = (size_t)NPTS*C_*2*2;  // pf_hi+pf_lo per instance
  int G = 1;
  if (Savail >= 8*perG) G = 8;
  else if (Savail >= 4*perG) G = 4;
  else if (Savail >= 2*perG) G = 2;

  // ---- stage A ----
  wtrans_split_kernel<<<dim3(C_/32, C_/32), 256, 0, stream>>>(s_w1, w1t_hi, w1t_lo, C_, C_);
  zero_kernel<<<16*NPTS/256, 256, 0, stream>>>(logit, 16*NPTS);
  for (int g0 = 0; g0 < 16; g0 += G) {
    hbf16* pf_hi = (hbf16*)S;
    hbf16* pf_lo = pf_hi + (size_t)G*NPTS*C_;
    sample_all_kernel<<<dim3(NPTS, G), 256, 0, stream>>>(other0, other1, brand,
        pf_hi, pf_lo, coords, g0);
    score_gemm_kernel<<<dim3(6, G*16), 256, 0, stream>>>((const short*)pf_hi, (const short*)pf_lo,
        (const short*)w1t_hi, (const short*)w1t_lo, s_b1, s_w2, logit + (size_t)g0*NPTS);
    topk_all_kernel<<<G, 64, 0, stream>>>(logit + (size_t)g0*NPTS, idxb + g0*8);
    softalign_all_kernel<<<dim3(TOPK_, G), 256, 0, stream>>>(mainx, pos, pf_hi, pf_lo,
        coords, idxb + g0*8, arand, mq, memf, g0);
  }

  // ---- stage B ----
  size_t total = (size_t)TOK_*C_;
  tgt0_kernel<<<(int)((total+255)/256), 256, 0, stream>>>(mainx, mq, pos, tgt);

  for (int l = 0; l < 2; ++l) {
    // ===== self-attention =====
    wtrans_kernel<<<dim3(3*C_/32, C_/32), 256, 0, stream>>>(sa_in_w + (size_t)l*C_*3*C_, wb0, C_, 3*C_);
    wtrans_kernel<<<dim3(C_/32, C_/32), 256, 0, stream>>>(sa_out_w + (size_t)l*C_*C_, wb1, C_, C_);
    for (int c0 = 0; c0 < B_; c0 += CH) {
      float* tgtc = tgt + (size_t)c0*HW_*C_;
      hbf16* abuf = (hbf16*)S;
      hbf16* qkv  = abuf + R*C_;
      hbf16* oatt = qkv + R*3*C_;
      hbf16* tmpb = oatt + R*C_;
      f2b_kernel<<<(int)((R*C_/4+255)/256), 256, 0, stream>>>(tgtc, abuf, (int)(R*C_));
      gemm_mfma_t<<<dim3(3*C_/128, (int)(R/128)), 256, 0, stream>>>((const short*)abuf, C_,
          (const short*)wb0, C_, sa_in_b + (size_t)l*3*C_, qkv, 3*C_, C_, 0);
      flash_attn_kernel<<<dim3(HW_/128, NH_, CH), 256, 0, stream>>>(qkv, oatt);
      gemm_mfma_t<<<dim3(C_/128, (int)(R/128)), 256, 0, stream>>>((const short*)oatt, C_,
          (const short*)wb1, C_, sa_out_b + (size_t)l*C_, tmpb, C_, C_, 0);
      ln_res_kernel<<<(int)R, 256, 0, stream>>>(tgtc, tmpb,
          ln_w + (size_t)(l*3+0)*C_, ln_b + (size_t)(l*3+0)*C_);
    }

    // ===== cross-attention =====
    wtrans_kernel<<<dim3(C_/32, C_/32), 256, 0, stream>>>(ca_in_w + (size_t)l*C_*3*C_, wb0, C_, 3*C_);
    wtrans_kernel<<<dim3(C_/32, C_/32), 256, 0, stream>>>(ca_out_w + (size_t)l*C_*C_, wb1, C_, C_);
    gemm_kernel<<<dim3((2*C_+BN-1)/BN, (80+BM-1)/BM), 256, 0, stream>>>(memf, C_,
        ca_in_w + (size_t)l*C_*3*C_ + C_, 3*C_, ca_in_b + (size_t)l*3*C_ + C_, kvm, 2*C_,
        80, 2*C_, C_, 0);
    for (int c0 = 0; c0 < B_; c0 += CH) {
      float* tgtc = tgt + (size_t)c0*HW_*C_;
      hbf16* abuf = (hbf16*)S;
      hbf16* qb   = abuf + R*C_;
      hbf16* tmpb = qb + R*C_;
      f2b_kernel<<<(int)((R*C_/4+255)/256), 256, 0, stream>>>(tgtc, abuf, (int)(R*C_));
      gemm_mfma_t<<<dim3(C_/128, (int)(R/128)), 256, 0, stream>>>((const short*)abuf, C_,
          (const short*)wb0, C_, ca_in_b + (size_t)l*3*C_, qb, C_, C_, 0);
      cross_attn_kernel<<<dim3(HW_, CH), 128, 0, stream>>>(qb, kvm, c0);
      gemm_mfma_t<<<dim3(C_/128, (int)(R/128)), 256, 0, stream>>>((const short*)qb, C_,
          (const short*)wb1, C_, ca_out_b + (size_t)l*C_, tmpb, C_, C_, 0);
      ln_res_kernel<<<(int)R, 256, 0, stream>>>(tgtc, tmpb,
          ln_w + (size_t)(l*3+1)*C_, ln_b + (size_t)(l*3+1)*C_);
    }

    // ===== FFN =====
    wtrans_kernel<<<dim3(FF_/32, C_/32), 256, 0, stream>>>(ff1_w + (size_t)l*C_*FF_, wb0, C_, FF_);
    wtrans_kernel<<<dim3(C_/32, FF_/32), 256, 0, stream>>>(ff2_w + (size_t)l*FF_*C_, wb1, FF_, C_);
    for (int c0 = 0; c0 < B_; c0 += CH) {
      float* tgtc = tgt + (size_t)c0*HW_*C_;
      hbf16* abuf = (hbf16*)S;
      hbf16* ffh  = abuf + R*C_;
      hbf16* tmpb = ffh + R*FF_;
      f2b_kernel<<<(int)((R*C_/4+255)/256), 256, 0, stream>>>(tgtc, abuf, (int)(R*C_));
      gemm_mfma_t<<<dim3(FF_/128, (int)(R/128)), 256, 0, stream>>>((const short*)abuf, C_,
          (const short*)wb0, C_, ff1_b + (size_t)l*FF_, ffh, FF_, C_, 1);
      gemm_mfma_t<<<dim3(C_/128, (int)(R/128)), 256, 0, stream>>>((const short*)ffh, FF_,
          (const short*)wb1, FF_, ff2_b + (size_t)l*C_, tmpb, C_, FF_, 0);
      ln_res_kernel<<<(int)R, 256, 0, stream>>>(tgtc, tmpb,
          ln_w + (size_t)(l*3+2)*C_, ln_b + (size_t)(l*3+2)*C_);
    }
  }

  out_kernel<<<(int)((total+255)/256), 256, 0, stream>>>(tgt, (float*)d_out);
}